// Round 2
// baseline (5004.262 us; speedup 1.0000x reference)
//
#include <hip/hip_runtime.h>
#include <cstdint>
#include <cstddef>

#define NE   1024    // N_EMBD
#define DF   4096    // D_FF
#define KACT 1024    // K_ACTIVE
#define NTOK 16384   // B*S

// ---------------------------------------------------------------------------
// Up-projection: z = silu(x @ Wg^T) * (x @ Wu^T)
// Tile: 128 tokens x 64 ff-channels, BK=16, 256 threads, 8x4 per-thread (x2).
// ---------------------------------------------------------------------------
__global__ __launch_bounds__(256) void k_gemm_gu(
    const float* __restrict__ x,   // [NTOK][NE]
    const float* __restrict__ Wg,  // [DF][NE]
    const float* __restrict__ Wu,  // [DF][NE]
    float* __restrict__ z,         // [CT][DF] (chunk base)
    int tok0)
{
    __shared__ float xs[16][128];
    __shared__ float gs[16][64];
    __shared__ float us[16][64];

    const int t  = threadIdx.x;
    const int m0 = blockIdx.x * 128;   // token tile (chunk-local)
    const int f0 = blockIdx.y * 64;    // ff tile

    const int xrow = t >> 1;           // 0..127
    const int xk   = (t & 1) * 8;      // 0 or 8
    const int wrow = t >> 2;           // 0..63
    const int wk   = (t & 3) * 4;      // 0,4,8,12

    const float* xg  = x  + (size_t)(tok0 + m0 + xrow) * NE + xk;
    const float* wgp = Wg + (size_t)(f0 + wrow) * NE + wk;
    const float* wup = Wu + (size_t)(f0 + wrow) * NE + wk;

    const int tx = t & 15;             // ff group (4 cols)
    const int ty = t >> 4;             // token group (8 rows)

    float ag[8][4] = {{0.f}};
    float au[8][4] = {{0.f}};

    for (int k0 = 0; k0 < NE; k0 += 16) {
        float4 xv0 = *(const float4*)(xg + k0);
        float4 xv1 = *(const float4*)(xg + k0 + 4);
        float4 gv  = *(const float4*)(wgp + k0);
        float4 uv  = *(const float4*)(wup + k0);
        __syncthreads();
        xs[xk+0][xrow] = xv0.x; xs[xk+1][xrow] = xv0.y;
        xs[xk+2][xrow] = xv0.z; xs[xk+3][xrow] = xv0.w;
        xs[xk+4][xrow] = xv1.x; xs[xk+5][xrow] = xv1.y;
        xs[xk+6][xrow] = xv1.z; xs[xk+7][xrow] = xv1.w;
        gs[wk+0][wrow] = gv.x;  gs[wk+1][wrow] = gv.y;
        gs[wk+2][wrow] = gv.z;  gs[wk+3][wrow] = gv.w;
        us[wk+0][wrow] = uv.x;  us[wk+1][wrow] = uv.y;
        us[wk+2][wrow] = uv.z;  us[wk+3][wrow] = uv.w;
        __syncthreads();
        #pragma unroll
        for (int k = 0; k < 16; ++k) {
            float4 a0 = *(const float4*)&xs[k][ty*8];
            float4 a1 = *(const float4*)&xs[k][ty*8+4];
            float4 bg = *(const float4*)&gs[k][tx*4];
            float4 bu = *(const float4*)&us[k][tx*4];
            float a[8]  = {a0.x,a0.y,a0.z,a0.w,a1.x,a1.y,a1.z,a1.w};
            float vg[4] = {bg.x,bg.y,bg.z,bg.w};
            float vu[4] = {bu.x,bu.y,bu.z,bu.w};
            #pragma unroll
            for (int i = 0; i < 8; ++i)
                #pragma unroll
                for (int j = 0; j < 4; ++j) {
                    ag[i][j] = fmaf(a[i], vg[j], ag[i][j]);
                    au[i][j] = fmaf(a[i], vu[j], au[i][j]);
                }
        }
    }

    #pragma unroll
    for (int i = 0; i < 8; ++i) {
        float4 zv;
        float* zp = (float*)&zv;
        #pragma unroll
        for (int j = 0; j < 4; ++j) {
            float g = ag[i][j], u = au[i][j];
            float s = g / (1.0f + expf(-g));   // silu
            zp[j] = s * u;
        }
        *(float4*)(z + (size_t)(m0 + ty*8 + i) * DF + f0 + tx*4) = zv;
    }
}

// ---------------------------------------------------------------------------
// Exact per-token top-K mask (jax.lax.top_k semantics on |z|, stable ties by
// ascending index). One block per token. Radix-select on bitcast(|z|).
// Masks z in place (non-selected -> 0).
// ---------------------------------------------------------------------------
__global__ __launch_bounds__(256) void k_topk_mask(float* __restrict__ z)
{
    __shared__ float    zrow[DF];      // 16 KB
    __shared__ unsigned hist[256];
    __shared__ int      cnts[256];
    __shared__ unsigned s_prefix;
    __shared__ int      s_remaining;

    const int t = threadIdx.x;
    float* zp = z + (size_t)blockIdx.x * DF;

    // load row
    for (int i = t; i < DF/4; i += 256)
        ((float4*)zrow)[i] = ((const float4*)zp)[i];
    if (t == 0) { s_prefix = 0u; s_remaining = KACT; }
    __syncthreads();

    // 4-pass radix select (8 bits/pass, MSB first) for the KACT-th largest key
    for (int pass = 3; pass >= 0; --pass) {
        const int shift = pass * 8;
        hist[t] = 0u;
        __syncthreads();
        const unsigned pfx = s_prefix;
        for (int i = t; i < DF; i += 256) {
            unsigned key = __float_as_uint(fabsf(zrow[i]));
            bool cand = (pass == 3) || ((key >> (shift + 8)) == pfx);
            if (cand) atomicAdd(&hist[(key >> shift) & 255u], 1u);
        }
        __syncthreads();
        if (t == 0) {
            int rem = s_remaining;
            int b = 255;
            for (; b > 0; --b) {
                int c = (int)hist[b];
                if (rem - c <= 0) break;
                rem -= c;
            }
            s_prefix = (pfx << 8) | (unsigned)b;
            s_remaining = rem;
        }
        __syncthreads();
    }

    const unsigned tkey = s_prefix;   // value of the K-th largest |z| (as bits)
    const int      E    = s_remaining; // how many ==tkey entries to keep

    // stable tie-break: rank ==tkey entries by ascending index
    const int base = t * 16;          // contiguous 16-element segment per thread
    int cnt = 0;
    #pragma unroll
    for (int j = 0; j < 16; ++j) {
        unsigned key = __float_as_uint(fabsf(zrow[base + j]));
        if (key == tkey) cnt++;
    }
    cnts[t] = cnt;
    __syncthreads();
    if (t == 0) {
        int run = 0;
        for (int i = 0; i < 256; ++i) { int c = cnts[i]; cnts[i] = run; run += c; }
    }
    __syncthreads();

    int rank = cnts[t];
    #pragma unroll
    for (int q = 0; q < 4; ++q) {
        float4 v;
        float* vp = (float*)&v;
        #pragma unroll
        for (int j = 0; j < 4; ++j) {
            int f = base + q*4 + j;
            float val = zrow[f];
            unsigned key = __float_as_uint(fabsf(val));
            bool sel;
            if (key > tkey)       sel = true;
            else if (key == tkey) { sel = (rank < E); rank++; }
            else                  sel = false;
            vp[j] = sel ? val : 0.0f;
        }
        *(float4*)(zp + base + q*4) = v;
    }
}

// ---------------------------------------------------------------------------
// Down-projection: out = z_masked @ Wd^T     (Wd is [NE][DF], f-contiguous)
// Tile: 128 tokens x 64 dims, BK=16, 256 threads, 8x4 per-thread.
// ---------------------------------------------------------------------------
__global__ __launch_bounds__(256) void k_gemm_down(
    const float* __restrict__ z,   // [CT][DF] masked
    const float* __restrict__ Wd,  // [NE][DF]
    float* __restrict__ out,       // [NTOK][NE]
    int tok0)
{
    __shared__ float zs[16][128];
    __shared__ float ws[16][64];

    const int t  = threadIdx.x;
    const int m0 = blockIdx.x * 128;
    const int d0 = blockIdx.y * 64;

    const int zrow = t >> 1;
    const int zk   = (t & 1) * 8;
    const int wrow = t >> 2;
    const int wk   = (t & 3) * 4;

    const float* zg = z  + (size_t)(m0 + zrow) * DF + zk;
    const float* wp = Wd + (size_t)(d0 + wrow) * DF + wk;

    const int tx = t & 15;
    const int ty = t >> 4;

    float acc[8][4] = {{0.f}};

    for (int k0 = 0; k0 < DF; k0 += 16) {
        float4 zv0 = *(const float4*)(zg + k0);
        float4 zv1 = *(const float4*)(zg + k0 + 4);
        float4 wv  = *(const float4*)(wp + k0);
        __syncthreads();
        zs[zk+0][zrow] = zv0.x; zs[zk+1][zrow] = zv0.y;
        zs[zk+2][zrow] = zv0.z; zs[zk+3][zrow] = zv0.w;
        zs[zk+4][zrow] = zv1.x; zs[zk+5][zrow] = zv1.y;
        zs[zk+6][zrow] = zv1.z; zs[zk+7][zrow] = zv1.w;
        ws[wk+0][wrow] = wv.x;  ws[wk+1][wrow] = wv.y;
        ws[wk+2][wrow] = wv.z;  ws[wk+3][wrow] = wv.w;
        __syncthreads();
        #pragma unroll
        for (int k = 0; k < 16; ++k) {
            float4 a0 = *(const float4*)&zs[k][ty*8];
            float4 a1 = *(const float4*)&zs[k][ty*8+4];
            float4 bv = *(const float4*)&ws[k][tx*4];
            float a[8] = {a0.x,a0.y,a0.z,a0.w,a1.x,a1.y,a1.z,a1.w};
            float b[4] = {bv.x,bv.y,bv.z,bv.w};
            #pragma unroll
            for (int i = 0; i < 8; ++i)
                #pragma unroll
                for (int j = 0; j < 4; ++j)
                    acc[i][j] = fmaf(a[i], b[j], acc[i][j]);
        }
    }

    #pragma unroll
    for (int i = 0; i < 8; ++i) {
        float4 ov = make_float4(acc[i][0], acc[i][1], acc[i][2], acc[i][3]);
        *(float4*)(out + (size_t)(tok0 + m0 + ty*8 + i) * NE + d0 + tx*4) = ov;
    }
}

// ---------------------------------------------------------------------------
extern "C" void kernel_launch(void* const* d_in, const int* in_sizes, int n_in,
                              void* d_out, int out_size, void* d_ws, size_t ws_size,
                              hipStream_t stream)
{
    const float* x  = (const float*)d_in[0];
    const float* Wg = (const float*)d_in[1];
    const float* Wu = (const float*)d_in[2];
    const float* Wd = (const float*)d_in[3];
    float* out  = (float*)d_out;
    float* zbuf = (float*)d_ws;

    // chunk tokens so the z scratch fits in ws
    int CT = NTOK;
    while (CT > 128 && (size_t)CT * DF * sizeof(float) > ws_size) CT >>= 1;

    for (int tok0 = 0; tok0 < NTOK; tok0 += CT) {
        k_gemm_gu  <<<dim3(CT/128, DF/64), 256, 0, stream>>>(x, Wg, Wu, zbuf, tok0);
        k_topk_mask<<<dim3(CT),            256, 0, stream>>>(zbuf);
        k_gemm_down<<<dim3(CT/128, NE/64), 256, 0, stream>>>(zbuf, Wd, out, tok0);
    }
}

// Round 3
// 2001.064 us; speedup vs baseline: 2.5008x; 2.5008x over previous
//
#include <hip/hip_runtime.h>
#include <cstdint>
#include <cstddef>

#define NE   1024    // N_EMBD
#define DF   4096    // D_FF
#define KACT 1024    // K_ACTIVE
#define NTOK 16384   // B*S

typedef _Float16 f16x8 __attribute__((ext_vector_type(8)));
typedef float    f32x4 __attribute__((ext_vector_type(4)));

#define MFMA(a,b,c) __builtin_amdgcn_mfma_f32_16x16x32_f16(a,b,c,0,0,0)

// split fp32 -> hi fp16 + lo fp16 (residual); a ~= h + l with |a - h - l| ~ 2^-22 |a|
__device__ __forceinline__ void cvt8(const float* f, f16x8& h, f16x8& l) {
    #pragma unroll
    for (int j = 0; j < 8; ++j) {
        _Float16 hh = (_Float16)f[j];
        h[j] = hh;
        l[j] = (_Float16)(f[j] - (float)hh);
    }
}

// ---------------------------------------------------------------------------
// Up-projection via fp16x3 MFMA: z = silu(x @ Wg^T) * (x @ Wu^T)
// BM=128 tokens, BN=64 ff, BK=32. 256 thr / 4 waves (2x2); per-wave 64x32 x2.
// LDS per buf: XH/XL [128][32], GH/GL/UH/UL [64][32] = 32KB; x2 bufs = 64KB.
// ---------------------------------------------------------------------------
#define OXH 0
#define OXL 4096
#define OGH 8192
#define OGL 10240
#define OUH 12288
#define OUL 14336
#define GUBUF 16384

__global__ __launch_bounds__(256) void k_gemm_gu_mfma(
    const float* __restrict__ x, const float* __restrict__ Wg,
    const float* __restrict__ Wu, float* __restrict__ z,
    int tok0, int nM)
{
    __shared__ _Float16 L[2 * GUBUF];
    const int t = threadIdx.x, lane = t & 63, wid = t >> 6;

    // 4x4 supertile swizzle for L2 locality (x-panel + W-panel ~ 4MB)
    int bid = blockIdx.x, mi, ni;
    if ((nM & 3) == 0) {
        int st = bid >> 4, lo = bid & 15, nstM = nM >> 2;
        mi = ((st % nstM) << 2) + (lo & 3);
        ni = ((st / nstM) << 2) + (lo >> 2);
    } else { mi = bid % nM; ni = bid / nM; }
    const int m0 = mi * 128, f0 = ni * 64;

    // staging thread mapping
    const int xr = t >> 1, xc = (t & 1) * 16;     // x: 128 rows x 32, 16 el/thr
    const int wr2 = t >> 2, wc2 = (t & 3) * 8;    // W: 64 rows x 32, 8 el/thr each
    const float* xsrc = x  + (size_t)(tok0 + m0 + xr) * NE + xc;
    const float* gsrc = Wg + (size_t)(f0 + wr2) * NE + wc2;
    const float* usrc = Wu + (size_t)(f0 + wr2) * NE + wc2;

    const int wr = wid >> 1, wc = wid & 1;
    const int lrow = lane & 15, lk = (lane >> 4) * 8;

    f32x4 accg[4][2] = {}, accu[4][2] = {};
    float xv[16], gv[8], uv[8];

    // prologue: load kt=0, cvt+write buf0
    #pragma unroll
    for (int q = 0; q < 4; ++q) *(float4*)&xv[q*4] = *(const float4*)(xsrc + q*4);
    *(float4*)&gv[0] = *(const float4*)(gsrc);  *(float4*)&gv[4] = *(const float4*)(gsrc + 4);
    *(float4*)&uv[0] = *(const float4*)(usrc);  *(float4*)&uv[4] = *(const float4*)(usrc + 4);
    {
        _Float16* Lb = L; f16x8 h, l;
        cvt8(&xv[0], h, l); *(f16x8*)&Lb[OXH + xr*32 + xc]     = h; *(f16x8*)&Lb[OXL + xr*32 + xc]     = l;
        cvt8(&xv[8], h, l); *(f16x8*)&Lb[OXH + xr*32 + xc + 8] = h; *(f16x8*)&Lb[OXL + xr*32 + xc + 8] = l;
        cvt8(gv, h, l);     *(f16x8*)&Lb[OGH + wr2*32 + wc2]   = h; *(f16x8*)&Lb[OGL + wr2*32 + wc2]   = l;
        cvt8(uv, h, l);     *(f16x8*)&Lb[OUH + wr2*32 + wc2]   = h; *(f16x8*)&Lb[OUL + wr2*32 + wc2]   = l;
    }
    __syncthreads();

    int buf = 0;
    for (int kt = 0; kt < 32; ++kt) {
        const bool more = (kt + 1 < 32);
        if (more) {   // T14: issue next-tile global loads before compute
            const float* xs2 = xsrc + (kt+1)*32;
            #pragma unroll
            for (int q = 0; q < 4; ++q) *(float4*)&xv[q*4] = *(const float4*)(xs2 + q*4);
            *(float4*)&gv[0] = *(const float4*)(gsrc + (kt+1)*32);
            *(float4*)&gv[4] = *(const float4*)(gsrc + (kt+1)*32 + 4);
            *(float4*)&uv[0] = *(const float4*)(usrc + (kt+1)*32);
            *(float4*)&uv[4] = *(const float4*)(usrc + (kt+1)*32 + 4);
        }
        const _Float16* Lb = &L[buf * GUBUF];
        f16x8 ah[4], al[4];
        #pragma unroll
        for (int mf = 0; mf < 4; ++mf) {
            int off = (wr*64 + mf*16 + lrow)*32 + lk;
            ah[mf] = *(const f16x8*)&Lb[OXH + off];
            al[mf] = *(const f16x8*)&Lb[OXL + off];
        }
        #pragma unroll
        for (int nf = 0; nf < 2; ++nf) {
            int offb = (wc*32 + nf*16 + lrow)*32 + lk;
            f16x8 bgh = *(const f16x8*)&Lb[OGH + offb];
            f16x8 bgl = *(const f16x8*)&Lb[OGL + offb];
            f16x8 buh = *(const f16x8*)&Lb[OUH + offb];
            f16x8 bul = *(const f16x8*)&Lb[OUL + offb];
            #pragma unroll
            for (int mf = 0; mf < 4; ++mf) {
                accg[mf][nf] = MFMA(ah[mf], bgh, accg[mf][nf]);
                accg[mf][nf] = MFMA(al[mf], bgh, accg[mf][nf]);
                accg[mf][nf] = MFMA(ah[mf], bgl, accg[mf][nf]);
                accu[mf][nf] = MFMA(ah[mf], buh, accu[mf][nf]);
                accu[mf][nf] = MFMA(al[mf], buh, accu[mf][nf]);
                accu[mf][nf] = MFMA(ah[mf], bul, accu[mf][nf]);
            }
        }
        if (more) {   // cvt + ds_write into the other buffer (safe: last read kt-1)
            _Float16* Lw = &L[(buf^1) * GUBUF]; f16x8 h, l;
            cvt8(&xv[0], h, l); *(f16x8*)&Lw[OXH + xr*32 + xc]     = h; *(f16x8*)&Lw[OXL + xr*32 + xc]     = l;
            cvt8(&xv[8], h, l); *(f16x8*)&Lw[OXH + xr*32 + xc + 8] = h; *(f16x8*)&Lw[OXL + xr*32 + xc + 8] = l;
            cvt8(gv, h, l);     *(f16x8*)&Lw[OGH + wr2*32 + wc2]   = h; *(f16x8*)&Lw[OGL + wr2*32 + wc2]   = l;
            cvt8(uv, h, l);     *(f16x8*)&Lw[OUH + wr2*32 + wc2]   = h; *(f16x8*)&Lw[OUL + wr2*32 + wc2]   = l;
        }
        __syncthreads();
        buf ^= 1;
    }

    // epilogue: silu(g)*u, fp32 store (C-frag: col=lane&15, row=(lane>>4)*4+r)
    #pragma unroll
    for (int mf = 0; mf < 4; ++mf)
        #pragma unroll
        for (int nf = 0; nf < 2; ++nf)
            #pragma unroll
            for (int r = 0; r < 4; ++r) {
                int row = m0 + wr*64 + mf*16 + (lane>>4)*4 + r;
                int col = f0 + wc*32 + nf*16 + lrow;
                float g = accg[mf][nf][r], u = accu[mf][nf][r];
                z[(size_t)row*DF + col] = (g / (1.0f + expf(-g))) * u;
            }
}

// ---------------------------------------------------------------------------
// Exact per-token top-K mask (unchanged from verified baseline).
// ---------------------------------------------------------------------------
__global__ __launch_bounds__(256) void k_topk_mask(float* __restrict__ z)
{
    __shared__ float    zrow[DF];
    __shared__ unsigned hist[256];
    __shared__ int      cnts[256];
    __shared__ unsigned s_prefix;
    __shared__ int      s_remaining;

    const int t = threadIdx.x;
    float* zp = z + (size_t)blockIdx.x * DF;

    for (int i = t; i < DF/4; i += 256)
        ((float4*)zrow)[i] = ((const float4*)zp)[i];
    if (t == 0) { s_prefix = 0u; s_remaining = KACT; }
    __syncthreads();

    for (int pass = 3; pass >= 0; --pass) {
        const int shift = pass * 8;
        hist[t] = 0u;
        __syncthreads();
        const unsigned pfx = s_prefix;
        for (int i = t; i < DF; i += 256) {
            unsigned key = __float_as_uint(fabsf(zrow[i]));
            bool cand = (pass == 3) || ((key >> (shift + 8)) == pfx);
            if (cand) atomicAdd(&hist[(key >> shift) & 255u], 1u);
        }
        __syncthreads();
        if (t == 0) {
            int rem = s_remaining;
            int b = 255;
            for (; b > 0; --b) {
                int c = (int)hist[b];
                if (rem - c <= 0) break;
                rem -= c;
            }
            s_prefix = (pfx << 8) | (unsigned)b;
            s_remaining = rem;
        }
        __syncthreads();
    }

    const unsigned tkey = s_prefix;
    const int      E    = s_remaining;

    const int base = t * 16;
    int cnt = 0;
    #pragma unroll
    for (int j = 0; j < 16; ++j) {
        unsigned key = __float_as_uint(fabsf(zrow[base + j]));
        if (key == tkey) cnt++;
    }
    cnts[t] = cnt;
    __syncthreads();
    if (t == 0) {
        int run = 0;
        for (int i = 0; i < 256; ++i) { int c = cnts[i]; cnts[i] = run; run += c; }
    }
    __syncthreads();

    int rank = cnts[t];
    #pragma unroll
    for (int q = 0; q < 4; ++q) {
        float4 v;
        float* vp = (float*)&v;
        #pragma unroll
        for (int j = 0; j < 4; ++j) {
            int f = base + q*4 + j;
            float val = zrow[f];
            unsigned key = __float_as_uint(fabsf(val));
            bool sel;
            if (key > tkey)       sel = true;
            else if (key == tkey) { sel = (rank < E); rank++; }
            else                  sel = false;
            vp[j] = sel ? val : 0.0f;
        }
        *(float4*)(zp + base + q*4) = v;
    }
}

// ---------------------------------------------------------------------------
// Down-projection via fp16x3 MFMA: out = z_masked @ Wd^T
// BM=128 tokens, BN=128 dims, BK=32 over DF. LDS ZH/ZL/WH/WL [128][32] x2.
// ---------------------------------------------------------------------------
#define OZH 0
#define OZL 4096
#define OWH 8192
#define OWL 12288
#define DNBUF 16384

__global__ __launch_bounds__(256) void k_gemm_down_mfma(
    const float* __restrict__ z, const float* __restrict__ Wd,
    float* __restrict__ out, int tok0, int nM)
{
    __shared__ _Float16 L[2 * DNBUF];
    const int t = threadIdx.x, lane = t & 63, wid = t >> 6;

    int bid = blockIdx.x, mi, ni;
    if ((nM & 3) == 0) {
        int st = bid >> 4, lo = bid & 15, nstM = nM >> 2;
        mi = ((st % nstM) << 2) + (lo & 3);
        ni = ((st / nstM) << 2) + (lo >> 2);
    } else { mi = bid % nM; ni = bid / nM; }
    const int m0 = mi * 128, d0 = ni * 128;

    const int zr = t >> 1, zc = (t & 1) * 16;   // 128 rows x 32, 16 el/thr (both tiles)
    const float* zsrc = z  + (size_t)(m0 + zr) * DF + zc;
    const float* wsrc = Wd + (size_t)(d0 + zr) * DF + zc;

    const int wr = wid >> 1, wc = wid & 1;
    const int lrow = lane & 15, lk = (lane >> 4) * 8;

    f32x4 acc[4][4] = {};
    float zv[16], wv[16];

    #pragma unroll
    for (int q = 0; q < 4; ++q) {
        *(float4*)&zv[q*4] = *(const float4*)(zsrc + q*4);
        *(float4*)&wv[q*4] = *(const float4*)(wsrc + q*4);
    }
    {
        _Float16* Lb = L; f16x8 h, l;
        cvt8(&zv[0], h, l); *(f16x8*)&Lb[OZH + zr*32 + zc]     = h; *(f16x8*)&Lb[OZL + zr*32 + zc]     = l;
        cvt8(&zv[8], h, l); *(f16x8*)&Lb[OZH + zr*32 + zc + 8] = h; *(f16x8*)&Lb[OZL + zr*32 + zc + 8] = l;
        cvt8(&wv[0], h, l); *(f16x8*)&Lb[OWH + zr*32 + zc]     = h; *(f16x8*)&Lb[OWL + zr*32 + zc]     = l;
        cvt8(&wv[8], h, l); *(f16x8*)&Lb[OWH + zr*32 + zc + 8] = h; *(f16x8*)&Lb[OWL + zr*32 + zc + 8] = l;
    }
    __syncthreads();

    int buf = 0;
    for (int kt = 0; kt < DF/32; ++kt) {
        const bool more = (kt + 1 < DF/32);
        if (more) {
            #pragma unroll
            for (int q = 0; q < 4; ++q) {
                *(float4*)&zv[q*4] = *(const float4*)(zsrc + (kt+1)*32 + q*4);
                *(float4*)&wv[q*4] = *(const float4*)(wsrc + (kt+1)*32 + q*4);
            }
        }
        const _Float16* Lb = &L[buf * DNBUF];
        f16x8 ah[4], al[4];
        #pragma unroll
        for (int mf = 0; mf < 4; ++mf) {
            int off = (wr*64 + mf*16 + lrow)*32 + lk;
            ah[mf] = *(const f16x8*)&Lb[OZH + off];
            al[mf] = *(const f16x8*)&Lb[OZL + off];
        }
        #pragma unroll
        for (int nf = 0; nf < 4; ++nf) {
            int offb = (wc*64 + nf*16 + lrow)*32 + lk;
            f16x8 bh = *(const f16x8*)&Lb[OWH + offb];
            f16x8 bl = *(const f16x8*)&Lb[OWL + offb];
            #pragma unroll
            for (int mf = 0; mf < 4; ++mf) {
                acc[mf][nf] = MFMA(ah[mf], bh, acc[mf][nf]);
                acc[mf][nf] = MFMA(al[mf], bh, acc[mf][nf]);
                acc[mf][nf] = MFMA(ah[mf], bl, acc[mf][nf]);
            }
        }
        if (more) {
            _Float16* Lw = &L[(buf^1) * DNBUF]; f16x8 h, l;
            cvt8(&zv[0], h, l); *(f16x8*)&Lw[OZH + zr*32 + zc]     = h; *(f16x8*)&Lw[OZL + zr*32 + zc]     = l;
            cvt8(&zv[8], h, l); *(f16x8*)&Lw[OZH + zr*32 + zc + 8] = h; *(f16x8*)&Lw[OZL + zr*32 + zc + 8] = l;
            cvt8(&wv[0], h, l); *(f16x8*)&Lw[OWH + zr*32 + zc]     = h; *(f16x8*)&Lw[OWL + zr*32 + zc]     = l;
            cvt8(&wv[8], h, l); *(f16x8*)&Lw[OWH + zr*32 + zc + 8] = h; *(f16x8*)&Lw[OWL + zr*32 + zc + 8] = l;
        }
        __syncthreads();
        buf ^= 1;
    }

    #pragma unroll
    for (int mf = 0; mf < 4; ++mf)
        #pragma unroll
        for (int nf = 0; nf < 4; ++nf)
            #pragma unroll
            for (int r = 0; r < 4; ++r) {
                int row = tok0 + m0 + wr*64 + mf*16 + (lane>>4)*4 + r;
                int col = d0 + wc*64 + nf*16 + lrow;
                out[(size_t)row*NE + col] = acc[mf][nf][r];
            }
}

// ---------------------------------------------------------------------------
extern "C" void kernel_launch(void* const* d_in, const int* in_sizes, int n_in,
                              void* d_out, int out_size, void* d_ws, size_t ws_size,
                              hipStream_t stream)
{
    const float* x  = (const float*)d_in[0];
    const float* Wg = (const float*)d_in[1];
    const float* Wu = (const float*)d_in[2];
    const float* Wd = (const float*)d_in[3];
    float* out  = (float*)d_out;
    float* zbuf = (float*)d_ws;

    int CT = NTOK;
    while (CT > 128 && (size_t)CT * DF * sizeof(float) > ws_size) CT >>= 1;

    for (int tok0 = 0; tok0 < NTOK; tok0 += CT) {
        int nM = CT / 128;
        k_gemm_gu_mfma  <<<dim3(nM * (DF/64)),  256, 0, stream>>>(x, Wg, Wu, zbuf, tok0, nM);
        k_topk_mask     <<<dim3(CT),            256, 0, stream>>>(zbuf);
        k_gemm_down_mfma<<<dim3(nM * (NE/128)), 256, 0, stream>>>(zbuf, Wd, out, tok0, nM);
    }
}

// Round 5
// 1827.643 us; speedup vs baseline: 2.7381x; 1.0949x over previous
//
#include <hip/hip_runtime.h>
#include <cstdint>
#include <cstddef>

#define NE   1024    // N_EMBD
#define DF   4096    // D_FF
#define KACT 1024    // K_ACTIVE
#define NTOK 16384   // B*S

// LDS rows are 32 f16 elements padded to 40 (80 B): bank-start = (20*row+4*slot)%32
// is exactly uniform over both the MFMA-fragment read pattern and the staging
// write pattern -> conflict-free (was 8-way with 64 B rows).
#define LROW 40

typedef _Float16 f16x8 __attribute__((ext_vector_type(8)));
typedef float    f32x4 __attribute__((ext_vector_type(4)));

#define MFMA(a,b,c) __builtin_amdgcn_mfma_f32_16x16x32_f16(a,b,c,0,0,0)

// split fp32 -> hi fp16 + lo fp16 (residual); |a - h - l| ~ 2^-22 |a|
__device__ __forceinline__ void cvt8(const float* f, f16x8& h, f16x8& l) {
    #pragma unroll
    for (int j = 0; j < 8; ++j) {
        _Float16 hh = (_Float16)f[j];
        h[j] = hh;
        l[j] = (_Float16)(f[j] - (float)hh);
    }
}

// ---------------------------------------------------------------------------
// Up-projection via fp16x3 MFMA: z = silu(x @ Wg^T) * (x @ Wu^T)
// BM=128 tokens, BN=64 ff, BK=32. 256 thr / 4 waves (2x2); per-wave 64x32 x2.
// LDS per buf: XH/XL [128][LROW], GH/GL/UH/UL [64][LROW] = 40KB; x2 = 80KB.
// ---------------------------------------------------------------------------
#define OXH 0
#define OXL (128*LROW)
#define OGH (2*128*LROW)
#define OGL (2*128*LROW + 64*LROW)
#define OUH (2*128*LROW + 2*64*LROW)
#define OUL (2*128*LROW + 3*64*LROW)
#define GUBUF (2*128*LROW + 4*64*LROW)   // 20480 elements = 40KB

__global__ __launch_bounds__(256) void k_gemm_gu_mfma(
    const float* __restrict__ x, const float* __restrict__ Wg,
    const float* __restrict__ Wu, float* __restrict__ z,
    int tok0, int nM)
{
    __shared__ _Float16 L[2 * GUBUF];
    const int t = threadIdx.x, lane = t & 63, wid = t >> 6;

    // 4x4 supertile swizzle for L2 locality
    int bid = blockIdx.x, mi, ni;
    if ((nM & 3) == 0) {
        int st = bid >> 4, lo = bid & 15, nstM = nM >> 2;
        mi = ((st % nstM) << 2) + (lo & 3);
        ni = ((st / nstM) << 2) + (lo >> 2);
    } else { mi = bid % nM; ni = bid / nM; }
    const int m0 = mi * 128, f0 = ni * 64;

    const int xr = t >> 1, xc = (t & 1) * 16;     // x: 128 rows x 32, 16 el/thr
    const int wr2 = t >> 2, wc2 = (t & 3) * 8;    // W: 64 rows x 32, 8 el/thr each
    const float* xsrc = x  + (size_t)(tok0 + m0 + xr) * NE + xc;
    const float* gsrc = Wg + (size_t)(f0 + wr2) * NE + wc2;
    const float* usrc = Wu + (size_t)(f0 + wr2) * NE + wc2;

    const int wr = wid >> 1, wc = wid & 1;
    const int lrow = lane & 15, lk = (lane >> 4) * 8;

    f32x4 accg[4][2] = {}, accu[4][2] = {};
    float xv[16], gv[8], uv[8];

    #pragma unroll
    for (int q = 0; q < 4; ++q) *(float4*)&xv[q*4] = *(const float4*)(xsrc + q*4);
    *(float4*)&gv[0] = *(const float4*)(gsrc);  *(float4*)&gv[4] = *(const float4*)(gsrc + 4);
    *(float4*)&uv[0] = *(const float4*)(usrc);  *(float4*)&uv[4] = *(const float4*)(usrc + 4);
    {
        _Float16* Lb = L; f16x8 h, l;
        cvt8(&xv[0], h, l); *(f16x8*)&Lb[OXH + xr*LROW + xc]     = h; *(f16x8*)&Lb[OXL + xr*LROW + xc]     = l;
        cvt8(&xv[8], h, l); *(f16x8*)&Lb[OXH + xr*LROW + xc + 8] = h; *(f16x8*)&Lb[OXL + xr*LROW + xc + 8] = l;
        cvt8(gv, h, l);     *(f16x8*)&Lb[OGH + wr2*LROW + wc2]   = h; *(f16x8*)&Lb[OGL + wr2*LROW + wc2]   = l;
        cvt8(uv, h, l);     *(f16x8*)&Lb[OUH + wr2*LROW + wc2]   = h; *(f16x8*)&Lb[OUL + wr2*LROW + wc2]   = l;
    }
    __syncthreads();

    int buf = 0;
    for (int kt = 0; kt < 32; ++kt) {
        const bool more = (kt + 1 < 32);
        if (more) {
            const float* xs2 = xsrc + (kt+1)*32;
            #pragma unroll
            for (int q = 0; q < 4; ++q) *(float4*)&xv[q*4] = *(const float4*)(xs2 + q*4);
            *(float4*)&gv[0] = *(const float4*)(gsrc + (kt+1)*32);
            *(float4*)&gv[4] = *(const float4*)(gsrc + (kt+1)*32 + 4);
            *(float4*)&uv[0] = *(const float4*)(usrc + (kt+1)*32);
            *(float4*)&uv[4] = *(const float4*)(usrc + (kt+1)*32 + 4);
        }
        const _Float16* Lb = &L[buf * GUBUF];
        f16x8 ah[4], al[4];
        #pragma unroll
        for (int mf = 0; mf < 4; ++mf) {
            int off = (wr*64 + mf*16 + lrow)*LROW + lk;
            ah[mf] = *(const f16x8*)&Lb[OXH + off];
            al[mf] = *(const f16x8*)&Lb[OXL + off];
        }
        #pragma unroll
        for (int nf = 0; nf < 2; ++nf) {
            int offb = (wc*32 + nf*16 + lrow)*LROW + lk;
            f16x8 bgh = *(const f16x8*)&Lb[OGH + offb];
            f16x8 bgl = *(const f16x8*)&Lb[OGL + offb];
            f16x8 buh = *(const f16x8*)&Lb[OUH + offb];
            f16x8 bul = *(const f16x8*)&Lb[OUL + offb];
            #pragma unroll
            for (int mf = 0; mf < 4; ++mf) {
                accg[mf][nf] = MFMA(ah[mf], bgh, accg[mf][nf]);
                accg[mf][nf] = MFMA(al[mf], bgh, accg[mf][nf]);
                accg[mf][nf] = MFMA(ah[mf], bgl, accg[mf][nf]);
                accu[mf][nf] = MFMA(ah[mf], buh, accu[mf][nf]);
                accu[mf][nf] = MFMA(al[mf], buh, accu[mf][nf]);
                accu[mf][nf] = MFMA(ah[mf], bul, accu[mf][nf]);
            }
        }
        if (more) {
            _Float16* Lw = &L[(buf^1) * GUBUF]; f16x8 h, l;
            cvt8(&xv[0], h, l); *(f16x8*)&Lw[OXH + xr*LROW + xc]     = h; *(f16x8*)&Lw[OXL + xr*LROW + xc]     = l;
            cvt8(&xv[8], h, l); *(f16x8*)&Lw[OXH + xr*LROW + xc + 8] = h; *(f16x8*)&Lw[OXL + xr*LROW + xc + 8] = l;
            cvt8(gv, h, l);     *(f16x8*)&Lw[OGH + wr2*LROW + wc2]   = h; *(f16x8*)&Lw[OGL + wr2*LROW + wc2]   = l;
            cvt8(uv, h, l);     *(f16x8*)&Lw[OUH + wr2*LROW + wc2]   = h; *(f16x8*)&Lw[OUL + wr2*LROW + wc2]   = l;
        }
        __syncthreads();
        buf ^= 1;
    }

    #pragma unroll
    for (int mf = 0; mf < 4; ++mf)
        #pragma unroll
        for (int nf = 0; nf < 2; ++nf)
            #pragma unroll
            for (int r = 0; r < 4; ++r) {
                int row = m0 + wr*64 + mf*16 + (lane>>4)*4 + r;
                int col = f0 + wc*32 + nf*16 + lrow;
                float g = accg[mf][nf][r], u = accu[mf][nf][r];
                z[(size_t)row*DF + col] = (g / (1.0f + expf(-g))) * u;
            }
}

// ---------------------------------------------------------------------------
// Exact per-token top-K mask. Reads fp32 row; writes MASKED row as fp16
// overlaid on the first half of the row's own fp32 storage (no cross-row
// hazard: each block owns its row). Down-GEMM reads the fp16 overlay.
// ---------------------------------------------------------------------------
__global__ __launch_bounds__(256) void k_topk_mask(float* __restrict__ z)
{
    __shared__ float    zrow[DF];
    __shared__ unsigned hist[256];
    __shared__ int      cnts[256];
    __shared__ unsigned s_prefix;
    __shared__ int      s_remaining;

    const int t = threadIdx.x;
    float* zp = z + (size_t)blockIdx.x * DF;

    for (int i = t; i < DF/4; i += 256)
        ((float4*)zrow)[i] = ((const float4*)zp)[i];
    if (t == 0) { s_prefix = 0u; s_remaining = KACT; }
    __syncthreads();

    for (int pass = 3; pass >= 0; --pass) {
        const int shift = pass * 8;
        hist[t] = 0u;
        __syncthreads();
        const unsigned pfx = s_prefix;
        for (int i = t; i < DF; i += 256) {
            unsigned key = __float_as_uint(fabsf(zrow[i]));
            bool cand = (pass == 3) || ((key >> (shift + 8)) == pfx);
            if (cand) atomicAdd(&hist[(key >> shift) & 255u], 1u);
        }
        __syncthreads();
        if (t == 0) {
            int rem = s_remaining;
            int b = 255;
            for (; b > 0; --b) {
                int c = (int)hist[b];
                if (rem - c <= 0) break;
                rem -= c;
            }
            s_prefix = (pfx << 8) | (unsigned)b;
            s_remaining = rem;
        }
        __syncthreads();
    }

    const unsigned tkey = s_prefix;
    const int      E    = s_remaining;

    const int base = t * 16;
    int cnt = 0;
    #pragma unroll
    for (int j = 0; j < 16; ++j) {
        unsigned key = __float_as_uint(fabsf(zrow[base + j]));
        if (key == tkey) cnt++;
    }
    cnts[t] = cnt;
    __syncthreads();
    if (t == 0) {
        int run = 0;
        for (int i = 0; i < 256; ++i) { int c = cnts[i]; cnts[i] = run; run += c; }
    }
    __syncthreads();

    int rank = cnts[t];
    _Float16* zp16 = (_Float16*)zp;   // fp16 overlay on own row
    #pragma unroll
    for (int q = 0; q < 2; ++q) {
        f16x8 v;
        #pragma unroll
        for (int j = 0; j < 8; ++j) {
            int f = base + q*8 + j;
            float val = zrow[f];
            unsigned key = __float_as_uint(fabsf(val));
            bool sel;
            if (key > tkey)       sel = true;
            else if (key == tkey) { sel = (rank < E); rank++; }
            else                  sel = false;
            v[j] = sel ? (_Float16)val : (_Float16)0.0f;
        }
        *(f16x8*)(zp16 + base + q*8) = v;
    }
}

// ---------------------------------------------------------------------------
// Down-projection, single fp16 MFMA (selection done; 2^-11 relative error on
// a 1024-term sum ~ 1e-3 absolute, far under threshold).
// BM=128, BN=128, BK=32. 4 waves (2x2); per-wave 64x64.
// z read as fp16 overlay (row byte-stride DF*4). LDS ZH/WH [128][LROW] x2 = 40KB.
// ---------------------------------------------------------------------------
#define OZH 0
#define OWH (128*LROW)
#define DNBUF (2*128*LROW)   // 10240 elements = 20KB

__global__ __launch_bounds__(256) void k_gemm_down_mfma(
    const float* __restrict__ z, const float* __restrict__ Wd,
    float* __restrict__ out, int tok0, int nM)
{
    __shared__ _Float16 L[2 * DNBUF];
    const int t = threadIdx.x, lane = t & 63, wid = t >> 6;

    int bid = blockIdx.x, mi, ni;
    if ((nM & 3) == 0) {
        int st = bid >> 4, lo = bid & 15, nstM = nM >> 2;
        mi = ((st % nstM) << 2) + (lo & 3);
        ni = ((st / nstM) << 2) + (lo >> 2);
    } else { mi = bid % nM; ni = bid / nM; }
    const int m0 = mi * 128, d0 = ni * 128;

    const int zr = t >> 1, zc = (t & 1) * 16;
    const _Float16* zsrc = (const _Float16*)((const char*)z + (size_t)(m0 + zr) * DF * 4) + zc;
    const float*    wsrc = Wd + (size_t)(d0 + zr) * DF + zc;

    const int wr = wid >> 1, wc = wid & 1;
    const int lrow = lane & 15, lk = (lane >> 4) * 8;

    f32x4 acc[4][4] = {};
    f16x8 zh0, zh1;
    float wv[16];

    zh0 = *(const f16x8*)(zsrc);
    zh1 = *(const f16x8*)(zsrc + 8);
    #pragma unroll
    for (int q = 0; q < 4; ++q) *(float4*)&wv[q*4] = *(const float4*)(wsrc + q*4);
    {
        _Float16* Lb = L;
        *(f16x8*)&Lb[OZH + zr*LROW + zc]     = zh0;
        *(f16x8*)&Lb[OZH + zr*LROW + zc + 8] = zh1;
        f16x8 h0, h1;
        #pragma unroll
        for (int j = 0; j < 8; ++j) { h0[j] = (_Float16)wv[j]; h1[j] = (_Float16)wv[8+j]; }
        *(f16x8*)&Lb[OWH + zr*LROW + zc]     = h0;
        *(f16x8*)&Lb[OWH + zr*LROW + zc + 8] = h1;
    }
    __syncthreads();

    int buf = 0;
    for (int kt = 0; kt < DF/32; ++kt) {
        const bool more = (kt + 1 < DF/32);
        if (more) {
            zh0 = *(const f16x8*)(zsrc + (kt+1)*32);
            zh1 = *(const f16x8*)(zsrc + (kt+1)*32 + 8);
            #pragma unroll
            for (int q = 0; q < 4; ++q)
                *(float4*)&wv[q*4] = *(const float4*)(wsrc + (kt+1)*32 + q*4);
        }
        const _Float16* Lb = &L[buf * DNBUF];
        f16x8 ah[4], bh[4];
        #pragma unroll
        for (int mf = 0; mf < 4; ++mf)
            ah[mf] = *(const f16x8*)&Lb[OZH + (wr*64 + mf*16 + lrow)*LROW + lk];
        #pragma unroll
        for (int nf = 0; nf < 4; ++nf)
            bh[nf] = *(const f16x8*)&Lb[OWH + (wc*64 + nf*16 + lrow)*LROW + lk];
        #pragma unroll
        for (int nf = 0; nf < 4; ++nf)
            #pragma unroll
            for (int mf = 0; mf < 4; ++mf)
                acc[mf][nf] = MFMA(ah[mf], bh[nf], acc[mf][nf]);
        if (more) {
            _Float16* Lw = &L[(buf^1) * DNBUF];
            *(f16x8*)&Lw[OZH + zr*LROW + zc]     = zh0;
            *(f16x8*)&Lw[OZH + zr*LROW + zc + 8] = zh1;
            f16x8 h0, h1;
            #pragma unroll
            for (int j = 0; j < 8; ++j) { h0[j] = (_Float16)wv[j]; h1[j] = (_Float16)wv[8+j]; }
            *(f16x8*)&Lw[OWH + zr*LROW + zc]     = h0;
            *(f16x8*)&Lw[OWH + zr*LROW + zc + 8] = h1;
        }
        __syncthreads();
        buf ^= 1;
    }

    #pragma unroll
    for (int mf = 0; mf < 4; ++mf)
        #pragma unroll
        for (int nf = 0; nf < 4; ++nf)
            #pragma unroll
            for (int r = 0; r < 4; ++r) {
                int row = tok0 + m0 + wr*64 + mf*16 + (lane>>4)*4 + r;
                int col = d0 + wc*64 + nf*16 + lrow;
                out[(size_t)row*NE + col] = acc[mf][nf][r];
            }
}

// ---------------------------------------------------------------------------
extern "C" void kernel_launch(void* const* d_in, const int* in_sizes, int n_in,
                              void* d_out, int out_size, void* d_ws, size_t ws_size,
                              hipStream_t stream)
{
    const float* x  = (const float*)d_in[0];
    const float* Wg = (const float*)d_in[1];
    const float* Wu = (const float*)d_in[2];
    const float* Wd = (const float*)d_in[3];
    float* out  = (float*)d_out;
    float* zbuf = (float*)d_ws;

    int CT = NTOK;
    while (CT > 128 && (size_t)CT * DF * sizeof(float) > ws_size) CT >>= 1;

    for (int tok0 = 0; tok0 < NTOK; tok0 += CT) {
        int nM = CT / 128;
        k_gemm_gu_mfma  <<<dim3(nM * (DF/64)),  256, 0, stream>>>(x, Wg, Wu, zbuf, tok0, nM);
        k_topk_mask     <<<dim3(CT),            256, 0, stream>>>(zbuf);
        k_gemm_down_mfma<<<dim3(nM * (NE/128)), 256, 0, stream>>>(zbuf, Wd, out, tok0, nM);
    }
}

// Round 6
// 1728.027 us; speedup vs baseline: 2.8959x; 1.0576x over previous
//
#include <hip/hip_runtime.h>
#include <cstdint>
#include <cstddef>

#define NE   1024    // N_EMBD
#define DF   4096    // D_FF
#define KACT 1024    // K_ACTIVE
#define NTOK 16384   // B*S

typedef _Float16 f16x8 __attribute__((ext_vector_type(8)));
typedef float    f32x4 __attribute__((ext_vector_type(4)));

#define MFMA(a,b,c) __builtin_amdgcn_mfma_f32_16x16x32_f16(a,b,c,0,0,0)

// LDS tiles are [rows][32] f16 (64 B rows). 16B-chunk slot XOR-swizzle:
// chunk' = chunk ^ ((row>>1)&3). Verified per-32-lane-phase uniform (8
// bank-slots x 4 touches) for A-frag reads, B-frag reads, and all staging
// writes -> minimum-cycle LDS ops. Same involution on write and read.
__device__ __forceinline__ int swz(int row, int lk) {
    return row * 32 + ((((lk) >> 3) ^ ((row >> 1) & 3)) << 3);
}

// split fp32 -> hi fp16 + lo fp16 (residual); |a - h - l| ~ 2^-22 |a|
__device__ __forceinline__ void cvt8(const float* f, f16x8& h, f16x8& l) {
    #pragma unroll
    for (int j = 0; j < 8; ++j) {
        _Float16 hh = (_Float16)f[j];
        h[j] = hh;
        l[j] = (_Float16)(f[j] - (float)hh);
    }
}

// ---------------------------------------------------------------------------
// Up-projection via fp16x3 MFMA: z = silu(x @ Wg^T) * (x @ Wu^T)
// BM=128 tokens, BN=64 ff, BK=32. 256 thr / 4 waves (2x2); per-wave 64x32 x2.
// LDS per buf: XH/XL [128][32], GH/GL/UH/UL [64][32] = 32KB; x2 = 64KB.
// ---------------------------------------------------------------------------
#define OXH 0
#define OXL (128*32)
#define OGH (2*128*32)
#define OGL (2*128*32 + 64*32)
#define OUH (2*128*32 + 2*64*32)
#define OUL (2*128*32 + 3*64*32)
#define GUBUF (2*128*32 + 4*64*32)   // 16384 elements = 32KB

__global__ __launch_bounds__(256) void k_gemm_gu_mfma(
    const float* __restrict__ x, const float* __restrict__ Wg,
    const float* __restrict__ Wu, float* __restrict__ z,
    int tok0, int nM)
{
    __shared__ _Float16 L[2 * GUBUF];
    const int t = threadIdx.x, lane = t & 63, wid = t >> 6;

    // 4x4 supertile swizzle for L2 locality
    int bid = blockIdx.x, mi, ni;
    if ((nM & 3) == 0) {
        int st = bid >> 4, lo = bid & 15, nstM = nM >> 2;
        mi = ((st % nstM) << 2) + (lo & 3);
        ni = ((st / nstM) << 2) + (lo >> 2);
    } else { mi = bid % nM; ni = bid / nM; }
    const int m0 = mi * 128, f0 = ni * 64;

    const int xr = t >> 1, xc = (t & 1) * 16;     // x: 128 rows x 32, 16 el/thr
    const int wr2 = t >> 2, wc2 = (t & 3) * 8;    // W: 64 rows x 32, 8 el/thr each
    const float* xsrc = x  + (size_t)(tok0 + m0 + xr) * NE + xc;
    const float* gsrc = Wg + (size_t)(f0 + wr2) * NE + wc2;
    const float* usrc = Wu + (size_t)(f0 + wr2) * NE + wc2;

    const int wr = wid >> 1, wc = wid & 1;
    const int lrow = lane & 15, lk = (lane >> 4) * 8;

    f32x4 accg[4][2] = {}, accu[4][2] = {};
    float xv[16], gv[8], uv[8];

    #pragma unroll
    for (int q = 0; q < 4; ++q) *(float4*)&xv[q*4] = *(const float4*)(xsrc + q*4);
    *(float4*)&gv[0] = *(const float4*)(gsrc);  *(float4*)&gv[4] = *(const float4*)(gsrc + 4);
    *(float4*)&uv[0] = *(const float4*)(usrc);  *(float4*)&uv[4] = *(const float4*)(usrc + 4);
    {
        _Float16* Lb = L; f16x8 h, l;
        cvt8(&xv[0], h, l); *(f16x8*)&Lb[OXH + swz(xr, xc)]     = h; *(f16x8*)&Lb[OXL + swz(xr, xc)]     = l;
        cvt8(&xv[8], h, l); *(f16x8*)&Lb[OXH + swz(xr, xc + 8)] = h; *(f16x8*)&Lb[OXL + swz(xr, xc + 8)] = l;
        cvt8(gv, h, l);     *(f16x8*)&Lb[OGH + swz(wr2, wc2)]   = h; *(f16x8*)&Lb[OGL + swz(wr2, wc2)]   = l;
        cvt8(uv, h, l);     *(f16x8*)&Lb[OUH + swz(wr2, wc2)]   = h; *(f16x8*)&Lb[OUL + swz(wr2, wc2)]   = l;
    }
    __syncthreads();

    int buf = 0;
    for (int kt = 0; kt < 32; ++kt) {
        const bool more = (kt + 1 < 32);
        if (more) {
            const float* xs2 = xsrc + (kt+1)*32;
            #pragma unroll
            for (int q = 0; q < 4; ++q) *(float4*)&xv[q*4] = *(const float4*)(xs2 + q*4);
            *(float4*)&gv[0] = *(const float4*)(gsrc + (kt+1)*32);
            *(float4*)&gv[4] = *(const float4*)(gsrc + (kt+1)*32 + 4);
            *(float4*)&uv[0] = *(const float4*)(usrc + (kt+1)*32);
            *(float4*)&uv[4] = *(const float4*)(usrc + (kt+1)*32 + 4);
        }
        const _Float16* Lb = &L[buf * GUBUF];
        f16x8 ah[4], al[4];
        #pragma unroll
        for (int mf = 0; mf < 4; ++mf) {
            int off = swz(wr*64 + mf*16 + lrow, lk);
            ah[mf] = *(const f16x8*)&Lb[OXH + off];
            al[mf] = *(const f16x8*)&Lb[OXL + off];
        }
        #pragma unroll
        for (int nf = 0; nf < 2; ++nf) {
            int offb = swz(wc*32 + nf*16 + lrow, lk);
            f16x8 bgh = *(const f16x8*)&Lb[OGH + offb];
            f16x8 bgl = *(const f16x8*)&Lb[OGL + offb];
            f16x8 buh = *(const f16x8*)&Lb[OUH + offb];
            f16x8 bul = *(const f16x8*)&Lb[OUL + offb];
            #pragma unroll
            for (int mf = 0; mf < 4; ++mf) {
                accg[mf][nf] = MFMA(ah[mf], bgh, accg[mf][nf]);
                accg[mf][nf] = MFMA(al[mf], bgh, accg[mf][nf]);
                accg[mf][nf] = MFMA(ah[mf], bgl, accg[mf][nf]);
                accu[mf][nf] = MFMA(ah[mf], buh, accu[mf][nf]);
                accu[mf][nf] = MFMA(al[mf], buh, accu[mf][nf]);
                accu[mf][nf] = MFMA(ah[mf], bul, accu[mf][nf]);
            }
        }
        if (more) {
            _Float16* Lw = &L[(buf^1) * GUBUF]; f16x8 h, l;
            cvt8(&xv[0], h, l); *(f16x8*)&Lw[OXH + swz(xr, xc)]     = h; *(f16x8*)&Lw[OXL + swz(xr, xc)]     = l;
            cvt8(&xv[8], h, l); *(f16x8*)&Lw[OXH + swz(xr, xc + 8)] = h; *(f16x8*)&Lw[OXL + swz(xr, xc + 8)] = l;
            cvt8(gv, h, l);     *(f16x8*)&Lw[OGH + swz(wr2, wc2)]   = h; *(f16x8*)&Lw[OGL + swz(wr2, wc2)]   = l;
            cvt8(uv, h, l);     *(f16x8*)&Lw[OUH + swz(wr2, wc2)]   = h; *(f16x8*)&Lw[OUL + swz(wr2, wc2)]   = l;
        }
        __syncthreads();
        buf ^= 1;
    }

    #pragma unroll
    for (int mf = 0; mf < 4; ++mf)
        #pragma unroll
        for (int nf = 0; nf < 2; ++nf)
            #pragma unroll
            for (int r = 0; r < 4; ++r) {
                int row = m0 + wr*64 + mf*16 + (lane>>4)*4 + r;
                int col = f0 + wc*32 + nf*16 + lrow;
                float g = accg[mf][nf][r], u = accu[mf][nf][r];
                z[(size_t)row*DF + col] = (g / (1.0f + expf(-g))) * u;
            }
}

// ---------------------------------------------------------------------------
// Exact per-token top-K mask. Reads fp32 row; writes MASKED row as fp16
// overlaid on the first half of the row's own fp32 storage (no cross-row
// hazard: each block owns its row). Down-GEMM reads the fp16 overlay.
// ---------------------------------------------------------------------------
__global__ __launch_bounds__(256) void k_topk_mask(float* __restrict__ z)
{
    __shared__ float    zrow[DF];
    __shared__ unsigned hist[256];
    __shared__ int      cnts[256];
    __shared__ unsigned s_prefix;
    __shared__ int      s_remaining;

    const int t = threadIdx.x;
    float* zp = z + (size_t)blockIdx.x * DF;

    for (int i = t; i < DF/4; i += 256)
        ((float4*)zrow)[i] = ((const float4*)zp)[i];
    if (t == 0) { s_prefix = 0u; s_remaining = KACT; }
    __syncthreads();

    for (int pass = 3; pass >= 0; --pass) {
        const int shift = pass * 8;
        hist[t] = 0u;
        __syncthreads();
        const unsigned pfx = s_prefix;
        for (int i = t; i < DF; i += 256) {
            unsigned key = __float_as_uint(fabsf(zrow[i]));
            bool cand = (pass == 3) || ((key >> (shift + 8)) == pfx);
            if (cand) atomicAdd(&hist[(key >> shift) & 255u], 1u);
        }
        __syncthreads();
        if (t == 0) {
            int rem = s_remaining;
            int b = 255;
            for (; b > 0; --b) {
                int c = (int)hist[b];
                if (rem - c <= 0) break;
                rem -= c;
            }
            s_prefix = (pfx << 8) | (unsigned)b;
            s_remaining = rem;
        }
        __syncthreads();
    }

    const unsigned tkey = s_prefix;
    const int      E    = s_remaining;

    const int base = t * 16;
    int cnt = 0;
    #pragma unroll
    for (int j = 0; j < 16; ++j) {
        unsigned key = __float_as_uint(fabsf(zrow[base + j]));
        if (key == tkey) cnt++;
    }
    cnts[t] = cnt;
    __syncthreads();
    if (t == 0) {
        int run = 0;
        for (int i = 0; i < 256; ++i) { int c = cnts[i]; cnts[i] = run; run += c; }
    }
    __syncthreads();

    int rank = cnts[t];
    _Float16* zp16 = (_Float16*)zp;   // fp16 overlay on own row
    #pragma unroll
    for (int q = 0; q < 2; ++q) {
        f16x8 v;
        #pragma unroll
        for (int j = 0; j < 8; ++j) {
            int f = base + q*8 + j;
            float val = zrow[f];
            unsigned key = __float_as_uint(fabsf(val));
            bool sel;
            if (key > tkey)       sel = true;
            else if (key == tkey) { sel = (rank < E); rank++; }
            else                  sel = false;
            v[j] = sel ? (_Float16)val : (_Float16)0.0f;
        }
        *(f16x8*)(zp16 + base + q*8) = v;
    }
}

// ---------------------------------------------------------------------------
// Down-projection, single fp16 MFMA (selection done; 2^-11 relative error on
// a 1024-term sum ~ 1e-3 absolute, far under threshold).
// BM=128, BN=128, BK=32. 4 waves (2x2); per-wave 64x64.
// z read as fp16 overlay (row byte-stride DF*4). LDS ZH/WH [128][32] x2 = 32KB.
// ---------------------------------------------------------------------------
#define OZH 0
#define OWH (128*32)
#define DNBUF (2*128*32)   // 8192 elements = 16KB

__global__ __launch_bounds__(256) void k_gemm_down_mfma(
    const float* __restrict__ z, const float* __restrict__ Wd,
    float* __restrict__ out, int tok0, int nM)
{
    __shared__ _Float16 L[2 * DNBUF];
    const int t = threadIdx.x, lane = t & 63, wid = t >> 6;

    int bid = blockIdx.x, mi, ni;
    if ((nM & 3) == 0) {
        int st = bid >> 4, lo = bid & 15, nstM = nM >> 2;
        mi = ((st % nstM) << 2) + (lo & 3);
        ni = ((st / nstM) << 2) + (lo >> 2);
    } else { mi = bid % nM; ni = bid / nM; }
    const int m0 = mi * 128, d0 = ni * 128;

    const int zr = t >> 1, zc = (t & 1) * 16;
    const _Float16* zsrc = (const _Float16*)((const char*)z + (size_t)(m0 + zr) * DF * 4) + zc;
    const float*    wsrc = Wd + (size_t)(d0 + zr) * DF + zc;

    const int wr = wid >> 1, wc = wid & 1;
    const int lrow = lane & 15, lk = (lane >> 4) * 8;

    f32x4 acc[4][4] = {};
    f16x8 zh0, zh1;
    float wv[16];

    zh0 = *(const f16x8*)(zsrc);
    zh1 = *(const f16x8*)(zsrc + 8);
    #pragma unroll
    for (int q = 0; q < 4; ++q) *(float4*)&wv[q*4] = *(const float4*)(wsrc + q*4);
    {
        _Float16* Lb = L;
        *(f16x8*)&Lb[OZH + swz(zr, zc)]     = zh0;
        *(f16x8*)&Lb[OZH + swz(zr, zc + 8)] = zh1;
        f16x8 h0, h1;
        #pragma unroll
        for (int j = 0; j < 8; ++j) { h0[j] = (_Float16)wv[j]; h1[j] = (_Float16)wv[8+j]; }
        *(f16x8*)&Lb[OWH + swz(zr, zc)]     = h0;
        *(f16x8*)&Lb[OWH + swz(zr, zc + 8)] = h1;
    }
    __syncthreads();

    int buf = 0;
    for (int kt = 0; kt < DF/32; ++kt) {
        const bool more = (kt + 1 < DF/32);
        if (more) {
            zh0 = *(const f16x8*)(zsrc + (kt+1)*32);
            zh1 = *(const f16x8*)(zsrc + (kt+1)*32 + 8);
            #pragma unroll
            for (int q = 0; q < 4; ++q)
                *(float4*)&wv[q*4] = *(const float4*)(wsrc + (kt+1)*32 + q*4);
        }
        const _Float16* Lb = &L[buf * DNBUF];
        f16x8 ah[4], bh[4];
        #pragma unroll
        for (int mf = 0; mf < 4; ++mf)
            ah[mf] = *(const f16x8*)&Lb[OZH + swz(wr*64 + mf*16 + lrow, lk)];
        #pragma unroll
        for (int nf = 0; nf < 4; ++nf)
            bh[nf] = *(const f16x8*)&Lb[OWH + swz(wc*64 + nf*16 + lrow, lk)];
        #pragma unroll
        for (int nf = 0; nf < 4; ++nf)
            #pragma unroll
            for (int mf = 0; mf < 4; ++mf)
                acc[mf][nf] = MFMA(ah[mf], bh[nf], acc[mf][nf]);
        if (more) {
            _Float16* Lw = &L[(buf^1) * DNBUF];
            *(f16x8*)&Lw[OZH + swz(zr, zc)]     = zh0;
            *(f16x8*)&Lw[OZH + swz(zr, zc + 8)] = zh1;
            f16x8 h0, h1;
            #pragma unroll
            for (int j = 0; j < 8; ++j) { h0[j] = (_Float16)wv[j]; h1[j] = (_Float16)wv[8+j]; }
            *(f16x8*)&Lw[OWH + swz(zr, zc)]     = h0;
            *(f16x8*)&Lw[OWH + swz(zr, zc + 8)] = h1;
        }
        __syncthreads();
        buf ^= 1;
    }

    #pragma unroll
    for (int mf = 0; mf < 4; ++mf)
        #pragma unroll
        for (int nf = 0; nf < 4; ++nf)
            #pragma unroll
            for (int r = 0; r < 4; ++r) {
                int row = tok0 + m0 + wr*64 + mf*16 + (lane>>4)*4 + r;
                int col = d0 + wc*64 + nf*16 + lrow;
                out[(size_t)row*NE + col] = acc[mf][nf][r];
            }
}

// ---------------------------------------------------------------------------
extern "C" void kernel_launch(void* const* d_in, const int* in_sizes, int n_in,
                              void* d_out, int out_size, void* d_ws, size_t ws_size,
                              hipStream_t stream)
{
    const float* x  = (const float*)d_in[0];
    const float* Wg = (const float*)d_in[1];
    const float* Wu = (const float*)d_in[2];
    const float* Wd = (const float*)d_in[3];
    float* out  = (float*)d_out;
    float* zbuf = (float*)d_ws;

    int CT = NTOK;
    while (CT > 128 && (size_t)CT * DF * sizeof(float) > ws_size) CT >>= 1;

    for (int tok0 = 0; tok0 < NTOK; tok0 += CT) {
        int nM = CT / 128;
        k_gemm_gu_mfma  <<<dim3(nM * (DF/64)),  256, 0, stream>>>(x, Wg, Wu, zbuf, tok0, nM);
        k_topk_mask     <<<dim3(CT),            256, 0, stream>>>(zbuf);
        k_gemm_down_mfma<<<dim3(nM * (NE/128)), 256, 0, stream>>>(zbuf, Wd, out, tok0, nM);
    }
}

// Round 7
// 1454.714 us; speedup vs baseline: 3.4400x; 1.1879x over previous
//
#include <hip/hip_runtime.h>
#include <cstdint>
#include <cstddef>

#define NE   1024    // N_EMBD
#define DF   4096    // D_FF
#define KACT 1024    // K_ACTIVE
#define NTOK 16384   // B*S

typedef _Float16 f16x8 __attribute__((ext_vector_type(8)));
typedef float    f32x4 __attribute__((ext_vector_type(4)));

#define MFMA(a,b,c) __builtin_amdgcn_mfma_f32_16x16x32_f16(a,b,c,0,0,0)

// async global->LDS, 16B per lane; LDS dest = uniform base + lane*16 (linear)
#define GLD16(gp, lp) __builtin_amdgcn_global_load_lds( \
    (const __attribute__((address_space(1))) unsigned int*)(gp), \
    (__attribute__((address_space(3))) unsigned int*)(lp), 16, 0, 0)

// LDS tiles are [rows][32] f16 (64 B rows, 4x 16B chunks). Chunk-slot XOR
// swizzle chunk' = chunk ^ ((row>>1)&3): measured 0 bank conflicts (r6).
// With global_load_lds the LDS fill is linear, so the swizzle is applied by
// pre-swizzling the per-lane GLOBAL source chunk (same involution on read).
__device__ __forceinline__ int swz(int row, int lk) {
    return row * 32 + ((((lk) >> 3) ^ ((row >> 1) & 3)) << 3);
}

// split fp32 -> hi fp16 + lo fp16 (residual); |a - h - l| ~ 2^-22 |a|
__device__ __forceinline__ void cvt8(const float* f, f16x8& h, f16x8& l) {
    #pragma unroll
    for (int j = 0; j < 8; ++j) {
        _Float16 hh = (_Float16)f[j];
        h[j] = hh;
        l[j] = (_Float16)(f[j] - (float)hh);
    }
}

// ---------------------------------------------------------------------------
// Prep: fp32 -> (h,l) fp16 split arrays; and fp32 -> fp16 single.
// ---------------------------------------------------------------------------
__global__ __launch_bounds__(256) void k_split2(
    const float* __restrict__ s, _Float16* __restrict__ h,
    _Float16* __restrict__ l, int n8)
{
    int i = blockIdx.x * 256 + threadIdx.x;
    if (i >= n8) return;
    float4 a = ((const float4*)s)[2*i], b = ((const float4*)s)[2*i+1];
    float f[8] = {a.x,a.y,a.z,a.w,b.x,b.y,b.z,b.w};
    f16x8 hh, ll; cvt8(f, hh, ll);
    ((f16x8*)h)[i] = hh; ((f16x8*)l)[i] = ll;
}

__global__ __launch_bounds__(256) void k_cvt1(
    const float* __restrict__ s, _Float16* __restrict__ h, int n8)
{
    int i = blockIdx.x * 256 + threadIdx.x;
    if (i >= n8) return;
    float4 a = ((const float4*)s)[2*i], b = ((const float4*)s)[2*i+1];
    float f[8] = {a.x,a.y,a.z,a.w,b.x,b.y,b.z,b.w};
    f16x8 hh;
    #pragma unroll
    for (int j = 0; j < 8; ++j) hh[j] = (_Float16)f[j];
    ((f16x8*)h)[i] = hh;
}

// ---------------------------------------------------------------------------
// Up-projection via fp16x3 MFMA from pre-split arrays, global_load_lds staged.
// BM=128 tokens, BN=64 ff, BK=32. 4 waves (2x2); per-wave 64x32 (g and u).
// LDS per buf: XH/XL [128][32], GH/GL/UH/UL [64][32] = 32KB; x2 = 64KB.
// Per wave per K-step: 8 GLD16 ops (2 XH + 2 XL + 4 of its W array).
// ---------------------------------------------------------------------------
#define OXH 0
#define OXL (128*32)
#define OGH (2*128*32)
#define OGL (2*128*32 + 64*32)
#define OUH (2*128*32 + 2*64*32)
#define OUL (2*128*32 + 3*64*32)
#define GUBUF (2*128*32 + 4*64*32)   // 16384 elements = 32KB

__global__ __launch_bounds__(256) void k_gemm_gu_mfma(
    const _Float16* __restrict__ xh, const _Float16* __restrict__ xl,
    const _Float16* __restrict__ gh, const _Float16* __restrict__ gl,
    const _Float16* __restrict__ uh, const _Float16* __restrict__ ul,
    float* __restrict__ z, int nM)
{
    __shared__ _Float16 L[2 * GUBUF];
    const int t = threadIdx.x, lane = t & 63, wid = t >> 6;

    // 4x4 supertile swizzle for L2 locality
    int bid = blockIdx.x, mi, ni;
    if ((nM & 3) == 0) {
        int st = bid >> 4, lo = bid & 15, nstM = nM >> 2;
        mi = ((st % nstM) << 2) + (lo & 3);
        ni = ((st / nstM) << 2) + (lo >> 2);
    } else { mi = bid % nM; ni = bid / nM; }
    const int m0 = mi * 128, f0 = ni * 64;

    // ---- staging roles (per lane): linear LDS fill, pre-swizzled source ----
    const int rr = lane >> 2, slot = lane & 3;
    size_t xoff[2];
    #pragma unroll
    for (int q = 0; q < 2; ++q) {
        int row = wid*32 + q*16 + rr;
        int ss  = slot ^ ((row >> 1) & 3);
        xoff[q] = (size_t)(m0 + row) * (NE*2) + ss*16;
    }
    const char* wsrc = (wid == 0) ? (const char*)gh : (wid == 1) ? (const char*)gl
                     : (wid == 2) ? (const char*)uh : (const char*)ul;
    const int wbase = (wid == 0) ? OGH : (wid == 1) ? OGL : (wid == 2) ? OUH : OUL;
    size_t woff[4];
    #pragma unroll
    for (int q = 0; q < 4; ++q) {
        int row = q*16 + rr;
        int ss  = slot ^ ((row >> 1) & 3);
        woff[q] = (size_t)(f0 + row) * (NE*2) + ss*16;
    }
    const char* xhB = (const char*)xh;
    const char* xlB = (const char*)xl;

    const int wr = wid >> 1, wc = wid & 1;
    const int lrow = lane & 15, lk = (lane >> 4) * 8;

    f32x4 accg[4][2] = {}, accu[4][2] = {};

    // stage K-step kt into buffer b
    #define GU_STAGE(b, kt) do {                                              \
        _Float16* Lb = L + (b) * GUBUF;                                       \
        size_t ka = (size_t)(kt) * 64;                                        \
        _Pragma("unroll")                                                     \
        for (int q = 0; q < 2; ++q) {                                         \
            GLD16(xhB + xoff[q] + ka, Lb + OXH + (wid*32 + q*16)*32);         \
            GLD16(xlB + xoff[q] + ka, Lb + OXL + (wid*32 + q*16)*32);         \
        }                                                                     \
        _Pragma("unroll")                                                     \
        for (int q = 0; q < 4; ++q)                                           \
            GLD16(wsrc + woff[q] + ka, Lb + wbase + q*16*32);                 \
    } while (0)

    GU_STAGE(0, 0);
    __syncthreads();   // compiler drains vmcnt+lgkmcnt before s_barrier

    int buf = 0;
    for (int kt = 0; kt < 32; ++kt) {
        if (kt + 1 < 32) GU_STAGE(buf ^ 1, kt + 1);
        const _Float16* Lb = &L[buf * GUBUF];
        f16x8 ah[4], al[4];
        #pragma unroll
        for (int mf = 0; mf < 4; ++mf) {
            int off = swz(wr*64 + mf*16 + lrow, lk);
            ah[mf] = *(const f16x8*)&Lb[OXH + off];
            al[mf] = *(const f16x8*)&Lb[OXL + off];
        }
        #pragma unroll
        for (int nf = 0; nf < 2; ++nf) {
            int offb = swz(wc*32 + nf*16 + lrow, lk);
            f16x8 bgh = *(const f16x8*)&Lb[OGH + offb];
            f16x8 bgl = *(const f16x8*)&Lb[OGL + offb];
            f16x8 buh = *(const f16x8*)&Lb[OUH + offb];
            f16x8 bul = *(const f16x8*)&Lb[OUL + offb];
            #pragma unroll
            for (int mf = 0; mf < 4; ++mf) {
                accg[mf][nf] = MFMA(ah[mf], bgh, accg[mf][nf]);
                accg[mf][nf] = MFMA(al[mf], bgh, accg[mf][nf]);
                accg[mf][nf] = MFMA(ah[mf], bgl, accg[mf][nf]);
                accu[mf][nf] = MFMA(ah[mf], buh, accu[mf][nf]);
                accu[mf][nf] = MFMA(al[mf], buh, accu[mf][nf]);
                accu[mf][nf] = MFMA(ah[mf], bul, accu[mf][nf]);
            }
        }
        __syncthreads();
        buf ^= 1;
    }

    #pragma unroll
    for (int mf = 0; mf < 4; ++mf)
        #pragma unroll
        for (int nf = 0; nf < 2; ++nf)
            #pragma unroll
            for (int r = 0; r < 4; ++r) {
                int row = m0 + wr*64 + mf*16 + (lane>>4)*4 + r;
                int col = f0 + wc*32 + nf*16 + lrow;
                float g = accg[mf][nf][r], u = accu[mf][nf][r];
                z[(size_t)row*DF + col] = (g / (1.0f + expf(-g))) * u;
            }
    #undef GU_STAGE
}

// ---------------------------------------------------------------------------
// Exact per-token top-K mask. Reads fp32 row; writes MASKED row as fp16
// overlaid on the first half of the row's own fp32 storage.
// ---------------------------------------------------------------------------
__global__ __launch_bounds__(256) void k_topk_mask(float* __restrict__ z)
{
    __shared__ float    zrow[DF];
    __shared__ unsigned hist[256];
    __shared__ int      cnts[256];
    __shared__ unsigned s_prefix;
    __shared__ int      s_remaining;

    const int t = threadIdx.x;
    float* zp = z + (size_t)blockIdx.x * DF;

    for (int i = t; i < DF/4; i += 256)
        ((float4*)zrow)[i] = ((const float4*)zp)[i];
    if (t == 0) { s_prefix = 0u; s_remaining = KACT; }
    __syncthreads();

    for (int pass = 3; pass >= 0; --pass) {
        const int shift = pass * 8;
        hist[t] = 0u;
        __syncthreads();
        const unsigned pfx = s_prefix;
        for (int i = t; i < DF; i += 256) {
            unsigned key = __float_as_uint(fabsf(zrow[i]));
            bool cand = (pass == 3) || ((key >> (shift + 8)) == pfx);
            if (cand) atomicAdd(&hist[(key >> shift) & 255u], 1u);
        }
        __syncthreads();
        if (t == 0) {
            int rem = s_remaining;
            int b = 255;
            for (; b > 0; --b) {
                int c = (int)hist[b];
                if (rem - c <= 0) break;
                rem -= c;
            }
            s_prefix = (pfx << 8) | (unsigned)b;
            s_remaining = rem;
        }
        __syncthreads();
    }

    const unsigned tkey = s_prefix;
    const int      E    = s_remaining;

    const int base = t * 16;
    int cnt = 0;
    #pragma unroll
    for (int j = 0; j < 16; ++j) {
        unsigned key = __float_as_uint(fabsf(zrow[base + j]));
        if (key == tkey) cnt++;
    }
    cnts[t] = cnt;
    __syncthreads();
    if (t == 0) {
        int run = 0;
        for (int i = 0; i < 256; ++i) { int c = cnts[i]; cnts[i] = run; run += c; }
    }
    __syncthreads();

    int rank = cnts[t];
    _Float16* zp16 = (_Float16*)zp;
    #pragma unroll
    for (int q = 0; q < 2; ++q) {
        f16x8 v;
        #pragma unroll
        for (int j = 0; j < 8; ++j) {
            int f = base + q*8 + j;
            float val = zrow[f];
            unsigned key = __float_as_uint(fabsf(val));
            bool sel;
            if (key > tkey)       sel = true;
            else if (key == tkey) { sel = (rank < E); rank++; }
            else                  sel = false;
            v[j] = sel ? (_Float16)val : (_Float16)0.0f;
        }
        *(f16x8*)(zp16 + base + q*8) = v;
    }
}

// ---------------------------------------------------------------------------
// Down-projection, single fp16 MFMA, global_load_lds staged.
// BM=128, BN=128, BK=32. 4 waves (2x2); per-wave 64x64.
// z read as fp16 overlay (row byte-stride DF*4); Wd pre-converted fp16.
// LDS ZH/WH [128][32] per buf = 16KB; x2 = 32KB. 4 ops/wave/K-step.
// ---------------------------------------------------------------------------
#define OZH 0
#define OWH (128*32)
#define DNBUF (2*128*32)   // 8192 elements = 16KB

__global__ __launch_bounds__(256) void k_gemm_down_mfma(
    const float* __restrict__ z, const _Float16* __restrict__ wdh,
    float* __restrict__ out, int tok0, int nM)
{
    __shared__ _Float16 L[2 * DNBUF];
    const int t = threadIdx.x, lane = t & 63, wid = t >> 6;

    int bid = blockIdx.x, mi, ni;
    if ((nM & 3) == 0) {
        int st = bid >> 4, lo = bid & 15, nstM = nM >> 2;
        mi = ((st % nstM) << 2) + (lo & 3);
        ni = ((st / nstM) << 2) + (lo >> 2);
    } else { mi = bid % nM; ni = bid / nM; }
    const int m0 = mi * 128, d0 = ni * 128;

    const int rr = lane >> 2, slot = lane & 3;
    size_t zoff[2], wof[2];
    #pragma unroll
    for (int q = 0; q < 2; ++q) {
        int row = wid*32 + q*16 + rr;
        int ss  = slot ^ ((row >> 1) & 3);
        zoff[q] = (size_t)(m0 + row) * (DF*4) + ss*16;   // fp16 overlay, fp32 row stride
        wof[q]  = (size_t)(d0 + row) * (DF*2) + ss*16;
    }
    const char* zB = (const char*)z;
    const char* wB = (const char*)wdh;

    const int wr = wid >> 1, wc = wid & 1;
    const int lrow = lane & 15, lk = (lane >> 4) * 8;

    f32x4 acc[4][4] = {};

    #define DN_STAGE(b, kt) do {                                              \
        _Float16* Lb = L + (b) * DNBUF;                                       \
        size_t ka = (size_t)(kt) * 64;                                        \
        _Pragma("unroll")                                                     \
        for (int q = 0; q < 2; ++q) {                                         \
            GLD16(zB + zoff[q] + ka, Lb + OZH + (wid*32 + q*16)*32);          \
            GLD16(wB + wof[q]  + ka, Lb + OWH + (wid*32 + q*16)*32);          \
        }                                                                     \
    } while (0)

    DN_STAGE(0, 0);
    __syncthreads();

    int buf = 0;
    for (int kt = 0; kt < DF/32; ++kt) {
        if (kt + 1 < DF/32) DN_STAGE(buf ^ 1, kt + 1);
        const _Float16* Lb = &L[buf * DNBUF];
        f16x8 ah[4], bh[4];
        #pragma unroll
        for (int mf = 0; mf < 4; ++mf)
            ah[mf] = *(const f16x8*)&Lb[OZH + swz(wr*64 + mf*16 + lrow, lk)];
        #pragma unroll
        for (int nf = 0; nf < 4; ++nf)
            bh[nf] = *(const f16x8*)&Lb[OWH + swz(wc*64 + nf*16 + lrow, lk)];
        #pragma unroll
        for (int nf = 0; nf < 4; ++nf)
            #pragma unroll
            for (int mf = 0; mf < 4; ++mf)
                acc[mf][nf] = MFMA(ah[mf], bh[nf], acc[mf][nf]);
        __syncthreads();
        buf ^= 1;
    }

    #pragma unroll
    for (int mf = 0; mf < 4; ++mf)
        #pragma unroll
        for (int nf = 0; nf < 4; ++nf)
            #pragma unroll
            for (int r = 0; r < 4; ++r) {
                int row = tok0 + m0 + wr*64 + mf*16 + (lane>>4)*4 + r;
                int col = d0 + wc*64 + nf*16 + lrow;
                out[(size_t)row*NE + col] = acc[mf][nf][r];
            }
    #undef DN_STAGE
}

// ---------------------------------------------------------------------------
extern "C" void kernel_launch(void* const* d_in, const int* in_sizes, int n_in,
                              void* d_out, int out_size, void* d_ws, size_t ws_size,
                              hipStream_t stream)
{
    const float* x  = (const float*)d_in[0];
    const float* Wg = (const float*)d_in[1];
    const float* Wu = (const float*)d_in[2];
    const float* Wd = (const float*)d_in[3];
    float* out = (float*)d_out;

    // fixed-size weight splits: gh/gl/uh/ul (DF*NE f16 each) + wdh (NE*DF f16)
    const size_t wElems = (size_t)DF * NE;
    const size_t fixedBytes = wElems * 2 * 5;   // 5 fp16 arrays = 40MB

    // chunk tokens: need z (CT*DF*4) + xh/xl (CT*NE*2 each) + fixed
    int CT = NTOK;
    while (CT > 128 &&
           (size_t)CT*DF*4 + (size_t)CT*NE*4 + fixedBytes > ws_size) CT >>= 1;

    char* wsb = (char*)d_ws;
    float*    zbuf = (float*)wsb;
    _Float16* xh   = (_Float16*)(wsb + (size_t)CT*DF*4);
    _Float16* xl   = xh + (size_t)CT*NE;
    _Float16* gh   = xl + (size_t)CT*NE;
    _Float16* gl   = gh + wElems;
    _Float16* uh   = gl + wElems;
    _Float16* ul   = uh + wElems;
    _Float16* wdh  = ul + wElems;

    // one-time weight prep
    {
        int n8 = (int)(wElems / 8);
        k_split2<<<dim3((n8+255)/256), 256, 0, stream>>>(Wg, gh, gl, n8);
        k_split2<<<dim3((n8+255)/256), 256, 0, stream>>>(Wu, uh, ul, n8);
        k_cvt1  <<<dim3((n8+255)/256), 256, 0, stream>>>(Wd, wdh, n8);
    }

    for (int tok0 = 0; tok0 < NTOK; tok0 += CT) {
        int nM = CT / 128;
        int nx8 = CT * NE / 8;
        k_split_x: ;
        k_split2<<<dim3((nx8+255)/256), 256, 0, stream>>>(x + (size_t)tok0*NE, xh, xl, nx8);
        k_gemm_gu_mfma  <<<dim3(nM * (DF/64)),  256, 0, stream>>>(xh, xl, gh, gl, uh, ul, zbuf, nM);
        k_topk_mask     <<<dim3(CT),            256, 0, stream>>>(zbuf);
        k_gemm_down_mfma<<<dim3(nM * (NE/128)), 256, 0, stream>>>(zbuf, wdh, out, tok0, nM);
    }
}

// Round 10
// 1183.514 us; speedup vs baseline: 4.2283x; 1.2291x over previous
//
#include <hip/hip_runtime.h>
#include <cstdint>
#include <cstddef>

#define NE   1024    // N_EMBD
#define DF   4096    // D_FF
#define KACT 1024    // K_ACTIVE
#define NTOK 16384   // B*S

typedef _Float16       f16x8  __attribute__((ext_vector_type(8)));
typedef unsigned short u16x8  __attribute__((ext_vector_type(8)));
typedef float          f32x4  __attribute__((ext_vector_type(4)));

#define MFMA(a,b,c) __builtin_amdgcn_mfma_f32_16x16x32_f16(a,b,c,0,0,0)

// async global->LDS, 16B per lane; LDS dest = uniform base + lane*16 (linear)
#define GLD16(gp, lp) __builtin_amdgcn_global_load_lds( \
    (const __attribute__((address_space(1))) unsigned int*)(gp), \
    (__attribute__((address_space(3))) unsigned int*)(lp), 16, 0, 0)

// LDS tiles are [rows][32] f16 (64 B rows, 4x 16B chunks). Chunk-slot XOR
// swizzle chunk' = chunk ^ ((row>>1)&3): measured 0 bank conflicts (r6).
// With global_load_lds the LDS fill is linear, so the swizzle is applied by
// pre-swizzling the per-lane GLOBAL source chunk (same involution on read).
__device__ __forceinline__ int swz(int row, int lk) {
    return row * 32 + ((((lk) >> 3) ^ ((row >> 1) & 3)) << 3);
}

// split fp32 -> hi fp16 + lo fp16 (residual); |a - h - l| ~ 2^-22 |a|
__device__ __forceinline__ void cvt8(const float* f, f16x8& h, f16x8& l) {
    #pragma unroll
    for (int j = 0; j < 8; ++j) {
        _Float16 hh = (_Float16)f[j];
        h[j] = hh;
        l[j] = (_Float16)(f[j] - (float)hh);
    }
}

// ---------------------------------------------------------------------------
// Prep: fp32 -> (h,l) fp16 split arrays; and fp32 -> fp16 single.
// ---------------------------------------------------------------------------
__global__ __launch_bounds__(256) void k_split2(
    const float* __restrict__ s, _Float16* __restrict__ h,
    _Float16* __restrict__ l, int n8)
{
    int i = blockIdx.x * 256 + threadIdx.x;
    if (i >= n8) return;
    float4 a = ((const float4*)s)[2*i], b = ((const float4*)s)[2*i+1];
    float f[8] = {a.x,a.y,a.z,a.w,b.x,b.y,b.z,b.w};
    f16x8 hh, ll; cvt8(f, hh, ll);
    ((f16x8*)h)[i] = hh; ((f16x8*)l)[i] = ll;
}

__global__ __launch_bounds__(256) void k_cvt1(
    const float* __restrict__ s, _Float16* __restrict__ h, int n8)
{
    int i = blockIdx.x * 256 + threadIdx.x;
    if (i >= n8) return;
    float4 a = ((const float4*)s)[2*i], b = ((const float4*)s)[2*i+1];
    float f[8] = {a.x,a.y,a.z,a.w,b.x,b.y,b.z,b.w};
    f16x8 hh;
    #pragma unroll
    for (int j = 0; j < 8; ++j) hh[j] = (_Float16)f[j];
    ((f16x8*)h)[i] = hh;
}

// ---------------------------------------------------------------------------
// Up-projection via fp16x3 MFMA from pre-split arrays, global_load_lds staged.
// BM=128 tokens, BN=64 ff, BK=32. 4 waves (2x2); per-wave 64x32 (g and u).
// LDS per buf: XH/XL [128][32], GH/GL/UH/UL [64][32] = 32KB; x2 = 64KB.
// Output z written as fp16.
// ---------------------------------------------------------------------------
#define OXH 0
#define OXL (128*32)
#define OGH (2*128*32)
#define OGL (2*128*32 + 64*32)
#define OUH (2*128*32 + 2*64*32)
#define OUL (2*128*32 + 3*64*32)
#define GUBUF (2*128*32 + 4*64*32)   // 16384 elements = 32KB

__global__ __launch_bounds__(256) void k_gemm_gu_mfma(
    const _Float16* __restrict__ xh, const _Float16* __restrict__ xl,
    const _Float16* __restrict__ gh, const _Float16* __restrict__ gl,
    const _Float16* __restrict__ uh, const _Float16* __restrict__ ul,
    _Float16* __restrict__ z, int nM)
{
    __shared__ _Float16 L[2 * GUBUF];
    const int t = threadIdx.x, lane = t & 63, wid = t >> 6;

    // 4x4 supertile swizzle for L2 locality
    int bid = blockIdx.x, mi, ni;
    if ((nM & 3) == 0) {
        int st = bid >> 4, lo = bid & 15, nstM = nM >> 2;
        mi = ((st % nstM) << 2) + (lo & 3);
        ni = ((st / nstM) << 2) + (lo >> 2);
    } else { mi = bid % nM; ni = bid / nM; }
    const int m0 = mi * 128, f0 = ni * 64;

    // ---- staging roles (per lane): linear LDS fill, pre-swizzled source ----
    const int rr = lane >> 2, slot = lane & 3;
    size_t xoff[2];
    #pragma unroll
    for (int q = 0; q < 2; ++q) {
        int row = wid*32 + q*16 + rr;
        int ss  = slot ^ ((row >> 1) & 3);
        xoff[q] = (size_t)(m0 + row) * (NE*2) + ss*16;
    }
    const char* wsrc = (wid == 0) ? (const char*)gh : (wid == 1) ? (const char*)gl
                     : (wid == 2) ? (const char*)uh : (const char*)ul;
    const int wbase = (wid == 0) ? OGH : (wid == 1) ? OGL : (wid == 2) ? OUH : OUL;
    size_t woff[4];
    #pragma unroll
    for (int q = 0; q < 4; ++q) {
        int row = q*16 + rr;
        int ss  = slot ^ ((row >> 1) & 3);
        woff[q] = (size_t)(f0 + row) * (NE*2) + ss*16;
    }
    const char* xhB = (const char*)xh;
    const char* xlB = (const char*)xl;

    const int wr = wid >> 1, wc = wid & 1;
    const int lrow = lane & 15, lk = (lane >> 4) * 8;

    f32x4 accg[4][2] = {}, accu[4][2] = {};

    // stage K-step kt into buffer b
    #define GU_STAGE(b, kt) do {                                              \
        _Float16* Lb = L + (b) * GUBUF;                                       \
        size_t ka = (size_t)(kt) * 64;                                        \
        _Pragma("unroll")                                                     \
        for (int q = 0; q < 2; ++q) {                                         \
            GLD16(xhB + xoff[q] + ka, Lb + OXH + (wid*32 + q*16)*32);         \
            GLD16(xlB + xoff[q] + ka, Lb + OXL + (wid*32 + q*16)*32);         \
        }                                                                     \
        _Pragma("unroll")                                                     \
        for (int q = 0; q < 4; ++q)                                           \
            GLD16(wsrc + woff[q] + ka, Lb + wbase + q*16*32);                 \
    } while (0)

    GU_STAGE(0, 0);
    __syncthreads();

    int buf = 0;
    for (int kt = 0; kt < 32; ++kt) {
        if (kt + 1 < 32) GU_STAGE(buf ^ 1, kt + 1);
        const _Float16* Lb = &L[buf * GUBUF];
        f16x8 ah[4], al[4];
        #pragma unroll
        for (int mf = 0; mf < 4; ++mf) {
            int off = swz(wr*64 + mf*16 + lrow, lk);
            ah[mf] = *(const f16x8*)&Lb[OXH + off];
            al[mf] = *(const f16x8*)&Lb[OXL + off];
        }
        #pragma unroll
        for (int nf = 0; nf < 2; ++nf) {
            int offb = swz(wc*32 + nf*16 + lrow, lk);
            f16x8 bgh = *(const f16x8*)&Lb[OGH + offb];
            f16x8 bgl = *(const f16x8*)&Lb[OGL + offb];
            f16x8 buh = *(const f16x8*)&Lb[OUH + offb];
            f16x8 bul = *(const f16x8*)&Lb[OUL + offb];
            #pragma unroll
            for (int mf = 0; mf < 4; ++mf) {
                accg[mf][nf] = MFMA(ah[mf], bgh, accg[mf][nf]);
                accg[mf][nf] = MFMA(al[mf], bgh, accg[mf][nf]);
                accg[mf][nf] = MFMA(ah[mf], bgl, accg[mf][nf]);
                accu[mf][nf] = MFMA(ah[mf], buh, accu[mf][nf]);
                accu[mf][nf] = MFMA(al[mf], buh, accu[mf][nf]);
                accu[mf][nf] = MFMA(ah[mf], bul, accu[mf][nf]);
            }
        }
        __syncthreads();
        buf ^= 1;
    }

    #pragma unroll
    for (int mf = 0; mf < 4; ++mf)
        #pragma unroll
        for (int nf = 0; nf < 2; ++nf)
            #pragma unroll
            for (int r = 0; r < 4; ++r) {
                int row = m0 + wr*64 + mf*16 + (lane>>4)*4 + r;
                int col = f0 + wc*32 + nf*16 + lrow;
                float g = accg[mf][nf][r], u = accu[mf][nf][r];
                z[(size_t)row*DF + col] = (_Float16)((g / (1.0f + expf(-g))) * u);
            }
    #undef GU_STAGE
}

// ---------------------------------------------------------------------------
// Exact per-token top-K mask on fp16 z: 2-pass radix select on the 15-bit
// magnitude key (fp16 bitcast is monotonic for non-negative values); stable
// ties by ascending index. Masks the fp16 row in place.
// FIX (r9 post-mortem): masked write-back now includes the per-thread `base`
// offset (was writing every thread to row elements [0,16), leaving the rest
// unmasked -> absmax 0.943).
// ---------------------------------------------------------------------------
__global__ __launch_bounds__(256) void k_topk_mask16(_Float16* __restrict__ z)
{
    __shared__ unsigned short zrow[DF];    // 8 KB (raw fp16 bits)
    __shared__ unsigned hist[256];
    __shared__ int      cnts[256];
    __shared__ unsigned s_b1;
    __shared__ unsigned s_tkey;
    __shared__ int      s_remaining;

    const int t = threadIdx.x;
    unsigned short* zp = (unsigned short*)(z + (size_t)blockIdx.x * DF);

    for (int i = t; i < DF/8; i += 256) {
        ((ushort4*)zrow)[2*i]   = ((const ushort4*)zp)[2*i];
        ((ushort4*)zrow)[2*i+1] = ((const ushort4*)zp)[2*i+1];
    }
    if (t == 0) s_remaining = KACT;
    __syncthreads();

    // pass 1: bins = key bits [14:7]
    hist[t] = 0u;
    __syncthreads();
    {
        const int base = t * 16;
        #pragma unroll
        for (int j = 0; j < 16; ++j) {
            unsigned key = zrow[base + j] & 0x7FFFu;
            atomicAdd(&hist[key >> 7], 1u);
        }
    }
    __syncthreads();
    if (t == 0) {
        int rem = s_remaining;
        int b = 255;
        for (; b > 0; --b) {
            int c = (int)hist[b];
            if (rem - c <= 0) break;
            rem -= c;
        }
        s_b1 = (unsigned)b;
        s_remaining = rem;
    }
    __syncthreads();

    // pass 2: among keys with bits[14:7]==b1, bins = key bits [6:0]
    const unsigned b1 = s_b1;
    hist[t] = 0u;
    __syncthreads();
    {
        const int base = t * 16;
        #pragma unroll
        for (int j = 0; j < 16; ++j) {
            unsigned key = zrow[base + j] & 0x7FFFu;
            if ((key >> 7) == b1) atomicAdd(&hist[key & 0x7Fu], 1u);
        }
    }
    __syncthreads();
    if (t == 0) {
        int rem = s_remaining;
        int b = 127;
        for (; b > 0; --b) {
            int c = (int)hist[b];
            if (rem - c <= 0) break;
            rem -= c;
        }
        s_tkey = (b1 << 7) | (unsigned)b;
        s_remaining = rem;
    }
    __syncthreads();

    const unsigned tkey = s_tkey;
    const int      E    = s_remaining;

    // stable tie-break: rank ==tkey entries by ascending index
    const int base = t * 16;
    int cnt = 0;
    #pragma unroll
    for (int j = 0; j < 16; ++j)
        if ((zrow[base + j] & 0x7FFFu) == tkey) cnt++;
    cnts[t] = cnt;
    __syncthreads();
    if (t == 0) {
        int run = 0;
        for (int i = 0; i < 256; ++i) { int c = cnts[i]; cnts[i] = run; run += c; }
    }
    __syncthreads();

    int rank = cnts[t];
    #pragma unroll
    for (int q = 0; q < 2; ++q) {
        u16x8 v;
        #pragma unroll
        for (int j = 0; j < 8; ++j) {
            int f = base + q*8 + j;
            unsigned short raw = zrow[f];
            unsigned key = raw & 0x7FFFu;
            bool sel;
            if (key > tkey)       sel = true;
            else if (key == tkey) { sel = (rank < E); rank++; }
            else                  sel = false;
            v[j] = sel ? raw : (unsigned short)0;
        }
        *(u16x8*)(zp + base + q*8) = v;   // base offset restored (r9 fix)
    }
}

// ---------------------------------------------------------------------------
// Down-projection, single fp16 MFMA, global_load_lds staged.
// BM=128, BN=128, BK=32. 4 waves (2x2); per-wave 64x64.
// z is a dense fp16 array [CT][DF]; Wd pre-converted fp16.
// LDS ZH/WH [128][32] per buf = 16KB; x2 = 32KB.
// ---------------------------------------------------------------------------
#define OZH 0
#define OWH (128*32)
#define DNBUF (2*128*32)   // 8192 elements = 16KB

__global__ __launch_bounds__(256) void k_gemm_down_mfma(
    const _Float16* __restrict__ z, const _Float16* __restrict__ wdh,
    float* __restrict__ out, int tok0, int nM)
{
    __shared__ _Float16 L[2 * DNBUF];
    const int t = threadIdx.x, lane = t & 63, wid = t >> 6;

    int bid = blockIdx.x, mi, ni;
    if ((nM & 3) == 0) {
        int st = bid >> 4, lo = bid & 15, nstM = nM >> 2;
        mi = ((st % nstM) << 2) + (lo & 3);
        ni = ((st / nstM) << 2) + (lo >> 2);
    } else { mi = bid % nM; ni = bid / nM; }
    const int m0 = mi * 128, d0 = ni * 128;

    const int rr = lane >> 2, slot = lane & 3;
    size_t zoff[2], wof[2];
    #pragma unroll
    for (int q = 0; q < 2; ++q) {
        int row = wid*32 + q*16 + rr;
        int ss  = slot ^ ((row >> 1) & 3);
        zoff[q] = (size_t)(m0 + row) * (DF*2) + ss*16;
        wof[q]  = (size_t)(d0 + row) * (DF*2) + ss*16;
    }
    const char* zB = (const char*)z;
    const char* wB = (const char*)wdh;

    const int wr = wid >> 1, wc = wid & 1;
    const int lrow = lane & 15, lk = (lane >> 4) * 8;

    f32x4 acc[4][4] = {};

    #define DN_STAGE(b, kt) do {                                              \
        _Float16* Lb = L + (b) * DNBUF;                                       \
        size_t ka = (size_t)(kt) * 64;                                        \
        _Pragma("unroll")                                                     \
        for (int q = 0; q < 2; ++q) {                                         \
            GLD16(zB + zoff[q] + ka, Lb + OZH + (wid*32 + q*16)*32);          \
            GLD16(wB + wof[q]  + ka, Lb + OWH + (wid*32 + q*16)*32);          \
        }                                                                     \
    } while (0)

    DN_STAGE(0, 0);
    __syncthreads();

    int buf = 0;
    for (int kt = 0; kt < DF/32; ++kt) {
        if (kt + 1 < DF/32) DN_STAGE(buf ^ 1, kt + 1);
        const _Float16* Lb = &L[buf * DNBUF];
        f16x8 ah[4], bh[4];
        #pragma unroll
        for (int mf = 0; mf < 4; ++mf)
            ah[mf] = *(const f16x8*)&Lb[OZH + swz(wr*64 + mf*16 + lrow, lk)];
        #pragma unroll
        for (int nf = 0; nf < 4; ++nf)
            bh[nf] = *(const f16x8*)&Lb[OWH + swz(wc*64 + nf*16 + lrow, lk)];
        #pragma unroll
        for (int nf = 0; nf < 4; ++nf)
            #pragma unroll
            for (int mf = 0; mf < 4; ++mf)
                acc[mf][nf] = MFMA(ah[mf], bh[nf], acc[mf][nf]);
        __syncthreads();
        buf ^= 1;
    }

    #pragma unroll
    for (int mf = 0; mf < 4; ++mf)
        #pragma unroll
        for (int nf = 0; nf < 4; ++nf)
            #pragma unroll
            for (int r = 0; r < 4; ++r) {
                int row = tok0 + m0 + wr*64 + mf*16 + (lane>>4)*4 + r;
                int col = d0 + wc*64 + nf*16 + lrow;
                out[(size_t)row*NE + col] = acc[mf][nf][r];
            }
    #undef DN_STAGE
}

// ---------------------------------------------------------------------------
extern "C" void kernel_launch(void* const* d_in, const int* in_sizes, int n_in,
                              void* d_out, int out_size, void* d_ws, size_t ws_size,
                              hipStream_t stream)
{
    const float* x  = (const float*)d_in[0];
    const float* Wg = (const float*)d_in[1];
    const float* Wu = (const float*)d_in[2];
    const float* Wd = (const float*)d_in[3];
    float* out = (float*)d_out;

    // fixed-size weight splits: gh/gl/uh/ul (DF*NE f16 each) + wdh (NE*DF f16)
    const size_t wElems = (size_t)DF * NE;
    const size_t fixedBytes = wElems * 2 * 5;   // 5 fp16 arrays = 40MB

    // chunk tokens: need z fp16 (CT*DF*2) + xh/xl (CT*NE*2 each) + fixed
    int CT = NTOK;
    while (CT > 128 &&
           (size_t)CT*DF*2 + (size_t)CT*NE*4 + fixedBytes > ws_size) CT >>= 1;

    char* wsb = (char*)d_ws;
    _Float16* zbuf = (_Float16*)wsb;
    _Float16* xh   = (_Float16*)(wsb + (size_t)CT*DF*2);
    _Float16* xl   = xh + (size_t)CT*NE;
    _Float16* gh   = xl + (size_t)CT*NE;
    _Float16* gl   = gh + wElems;
    _Float16* uh   = gl + wElems;
    _Float16* ul   = uh + wElems;
    _Float16* wdh  = ul + wElems;

    // one-time weight prep
    {
        int n8 = (int)(wElems / 8);
        k_split2<<<dim3((n8+255)/256), 256, 0, stream>>>(Wg, gh, gl, n8);
        k_split2<<<dim3((n8+255)/256), 256, 0, stream>>>(Wu, uh, ul, n8);
        k_cvt1  <<<dim3((n8+255)/256), 256, 0, stream>>>(Wd, wdh, n8);
    }

    for (int tok0 = 0; tok0 < NTOK; tok0 += CT) {
        int nM = CT / 128;
        int nx8 = CT * NE / 8;
        k_split2<<<dim3((nx8+255)/256), 256, 0, stream>>>(x + (size_t)tok0*NE, xh, xl, nx8);
        k_gemm_gu_mfma  <<<dim3(nM * (DF/64)),  256, 0, stream>>>(xh, xl, gh, gl, uh, ul, zbuf, nM);
        k_topk_mask16   <<<dim3(CT),            256, 0, stream>>>(zbuf);
        k_gemm_down_mfma<<<dim3(nM * (NE/128)), 256, 0, stream>>>(zbuf, wdh, out, tok0, nM);
    }
}

// Round 11
// 991.570 us; speedup vs baseline: 5.0468x; 1.1936x over previous
//
#include <hip/hip_runtime.h>
#include <cstdint>
#include <cstddef>

#define NE   1024    // N_EMBD
#define DF   4096    // D_FF
#define KACT 1024    // K_ACTIVE
#define NTOK 16384   // B*S

typedef _Float16       f16x8  __attribute__((ext_vector_type(8)));
typedef unsigned short u16x8  __attribute__((ext_vector_type(8)));
typedef float          f32x4  __attribute__((ext_vector_type(4)));

#define MFMA(a,b,c) __builtin_amdgcn_mfma_f32_16x16x32_f16(a,b,c,0,0,0)

// async global->LDS, 16B per lane; LDS dest = uniform base + lane*16 (linear)
#define GLD16(gp, lp) __builtin_amdgcn_global_load_lds( \
    (const __attribute__((address_space(1))) unsigned int*)(gp), \
    (__attribute__((address_space(3))) unsigned int*)(lp), 16, 0, 0)

// LDS tiles are [rows][32] f16 (64 B rows, 4x 16B chunks). Chunk-slot XOR
// swizzle chunk' = chunk ^ ((row>>1)&3): measured 0 bank conflicts (r6).
// With global_load_lds the LDS fill is linear, so the swizzle is applied by
// pre-swizzling the per-lane GLOBAL source chunk (same involution on read).
__device__ __forceinline__ int swz(int row, int lk) {
    return row * 32 + ((((lk) >> 3) ^ ((row >> 1) & 3)) << 3);
}

// split fp32 -> hi fp16 + lo fp16 (residual); |a - h - l| ~ 2^-22 |a|
__device__ __forceinline__ void cvt8(const float* f, f16x8& h, f16x8& l) {
    #pragma unroll
    for (int j = 0; j < 8; ++j) {
        _Float16 hh = (_Float16)f[j];
        h[j] = hh;
        l[j] = (_Float16)(f[j] - (float)hh);
    }
}

// ---------------------------------------------------------------------------
// Prep: fp32 -> (h,l) fp16 split arrays; and fp32 -> fp16 single.
// ---------------------------------------------------------------------------
__global__ __launch_bounds__(256) void k_split2(
    const float* __restrict__ s, _Float16* __restrict__ h,
    _Float16* __restrict__ l, int n8)
{
    int i = blockIdx.x * 256 + threadIdx.x;
    if (i >= n8) return;
    float4 a = ((const float4*)s)[2*i], b = ((const float4*)s)[2*i+1];
    float f[8] = {a.x,a.y,a.z,a.w,b.x,b.y,b.z,b.w};
    f16x8 hh, ll; cvt8(f, hh, ll);
    ((f16x8*)h)[i] = hh; ((f16x8*)l)[i] = ll;
}

__global__ __launch_bounds__(256) void k_cvt1(
    const float* __restrict__ s, _Float16* __restrict__ h, int n8)
{
    int i = blockIdx.x * 256 + threadIdx.x;
    if (i >= n8) return;
    float4 a = ((const float4*)s)[2*i], b = ((const float4*)s)[2*i+1];
    float f[8] = {a.x,a.y,a.z,a.w,b.x,b.y,b.z,b.w};
    f16x8 hh;
    #pragma unroll
    for (int j = 0; j < 8; ++j) hh[j] = (_Float16)f[j];
    ((f16x8*)h)[i] = hh;
}

// ---------------------------------------------------------------------------
// Up-projection via fp16x2 MFMA (x split h+l, weights single fp16):
//   acc = xh*W + xl*W.  Dropped xh*Wl term: sigma(z-err) ~ 2.8e-4, same order
//   as the fp16 z-store rounding already accepted (r10 absmax 0.047).
// BM=128 tokens, BN=64 ff, BK=32. 4 waves (2x2); per-wave 64x32 (g and u).
// LDS per buf: XH/XL [128][32], GH/UH [64][32] = 24KB; x2 = 48KB (3 blk/CU).
// 32 MFMA + 12 ds_read_b128 + 6 GLD16 per wave per K-step.
// ---------------------------------------------------------------------------
#define OXH 0
#define OXL (128*32)
#define OGH (2*128*32)
#define OUH (2*128*32 + 64*32)
#define GUBUF (2*128*32 + 2*64*32)   // 12288 elements = 24KB

__global__ __launch_bounds__(256) void k_gemm_gu_mfma(
    const _Float16* __restrict__ xh, const _Float16* __restrict__ xl,
    const _Float16* __restrict__ gh, const _Float16* __restrict__ uh,
    _Float16* __restrict__ z, int nM)
{
    __shared__ _Float16 L[2 * GUBUF];
    const int t = threadIdx.x, lane = t & 63, wid = t >> 6;

    // 4x4 supertile swizzle for L2 locality
    int bid = blockIdx.x, mi, ni;
    if ((nM & 3) == 0) {
        int st = bid >> 4, lo = bid & 15, nstM = nM >> 2;
        mi = ((st % nstM) << 2) + (lo & 3);
        ni = ((st / nstM) << 2) + (lo >> 2);
    } else { mi = bid % nM; ni = bid / nM; }
    const int m0 = mi * 128, f0 = ni * 64;

    // ---- staging roles (per lane): linear LDS fill, pre-swizzled source ----
    const int rr = lane >> 2, slot = lane & 3;
    size_t xoff[2];
    #pragma unroll
    for (int q = 0; q < 2; ++q) {
        int row = wid*32 + q*16 + rr;
        int ss  = slot ^ ((row >> 1) & 3);
        xoff[q] = (size_t)(m0 + row) * (NE*2) + ss*16;
    }
    size_t woff;   // wave w stages GH and UH rows [w*16, w*16+16)
    {
        int row = wid*16 + rr;
        int ss  = slot ^ ((row >> 1) & 3);
        woff = (size_t)(f0 + row) * (NE*2) + ss*16;
    }
    const char* xhB = (const char*)xh;
    const char* xlB = (const char*)xl;
    const char* ghB = (const char*)gh;
    const char* uhB = (const char*)uh;

    const int wr = wid >> 1, wc = wid & 1;
    const int lrow = lane & 15, lk = (lane >> 4) * 8;

    f32x4 accg[4][2] = {}, accu[4][2] = {};

    // stage K-step kt into buffer b (6 GLD16 per lane)
    #define GU_STAGE(b, kt) do {                                              \
        _Float16* Lb = L + (b) * GUBUF;                                       \
        size_t ka = (size_t)(kt) * 64;                                        \
        _Pragma("unroll")                                                     \
        for (int q = 0; q < 2; ++q) {                                         \
            GLD16(xhB + xoff[q] + ka, Lb + OXH + (wid*32 + q*16)*32);         \
            GLD16(xlB + xoff[q] + ka, Lb + OXL + (wid*32 + q*16)*32);         \
        }                                                                     \
        GLD16(ghB + woff + ka, Lb + OGH + (wid*16)*32);                       \
        GLD16(uhB + woff + ka, Lb + OUH + (wid*16)*32);                       \
    } while (0)

    GU_STAGE(0, 0);
    __syncthreads();

    int buf = 0;
    for (int kt = 0; kt < 32; ++kt) {
        if (kt + 1 < 32) GU_STAGE(buf ^ 1, kt + 1);
        const _Float16* Lb = &L[buf * GUBUF];
        f16x8 ah[4], al[4];
        #pragma unroll
        for (int mf = 0; mf < 4; ++mf) {
            int off = swz(wr*64 + mf*16 + lrow, lk);
            ah[mf] = *(const f16x8*)&Lb[OXH + off];
            al[mf] = *(const f16x8*)&Lb[OXL + off];
        }
        #pragma unroll
        for (int nf = 0; nf < 2; ++nf) {
            int offb = swz(wc*32 + nf*16 + lrow, lk);
            f16x8 bgh = *(const f16x8*)&Lb[OGH + offb];
            f16x8 buh = *(const f16x8*)&Lb[OUH + offb];
            #pragma unroll
            for (int mf = 0; mf < 4; ++mf) {
                accg[mf][nf] = MFMA(ah[mf], bgh, accg[mf][nf]);
                accg[mf][nf] = MFMA(al[mf], bgh, accg[mf][nf]);
                accu[mf][nf] = MFMA(ah[mf], buh, accu[mf][nf]);
                accu[mf][nf] = MFMA(al[mf], buh, accu[mf][nf]);
            }
        }
        __syncthreads();
        buf ^= 1;
    }

    #pragma unroll
    for (int mf = 0; mf < 4; ++mf)
        #pragma unroll
        for (int nf = 0; nf < 2; ++nf)
            #pragma unroll
            for (int r = 0; r < 4; ++r) {
                int row = m0 + wr*64 + mf*16 + (lane>>4)*4 + r;
                int col = f0 + wc*32 + nf*16 + lrow;
                float g = accg[mf][nf][r], u = accu[mf][nf][r];
                z[(size_t)row*DF + col] = (_Float16)((g / (1.0f + expf(-g))) * u);
            }
    #undef GU_STAGE
}

// ---------------------------------------------------------------------------
// Exact per-token top-K mask on fp16 z: 2-pass radix select on the 15-bit
// magnitude key (fp16 bitcast is monotonic for non-negative values); stable
// ties by ascending index. Masks the fp16 row in place.
// ---------------------------------------------------------------------------
__global__ __launch_bounds__(256) void k_topk_mask16(_Float16* __restrict__ z)
{
    __shared__ unsigned short zrow[DF];    // 8 KB (raw fp16 bits)
    __shared__ unsigned hist[256];
    __shared__ int      cnts[256];
    __shared__ unsigned s_b1;
    __shared__ unsigned s_tkey;
    __shared__ int      s_remaining;

    const int t = threadIdx.x;
    unsigned short* zp = (unsigned short*)(z + (size_t)blockIdx.x * DF);

    for (int i = t; i < DF/8; i += 256) {
        ((ushort4*)zrow)[2*i]   = ((const ushort4*)zp)[2*i];
        ((ushort4*)zrow)[2*i+1] = ((const ushort4*)zp)[2*i+1];
    }
    if (t == 0) s_remaining = KACT;
    __syncthreads();

    // pass 1: bins = key bits [14:7]
    hist[t] = 0u;
    __syncthreads();
    {
        const int base = t * 16;
        #pragma unroll
        for (int j = 0; j < 16; ++j) {
            unsigned key = zrow[base + j] & 0x7FFFu;
            atomicAdd(&hist[key >> 7], 1u);
        }
    }
    __syncthreads();
    if (t == 0) {
        int rem = s_remaining;
        int b = 255;
        for (; b > 0; --b) {
            int c = (int)hist[b];
            if (rem - c <= 0) break;
            rem -= c;
        }
        s_b1 = (unsigned)b;
        s_remaining = rem;
    }
    __syncthreads();

    // pass 2: among keys with bits[14:7]==b1, bins = key bits [6:0]
    const unsigned b1 = s_b1;
    hist[t] = 0u;
    __syncthreads();
    {
        const int base = t * 16;
        #pragma unroll
        for (int j = 0; j < 16; ++j) {
            unsigned key = zrow[base + j] & 0x7FFFu;
            if ((key >> 7) == b1) atomicAdd(&hist[key & 0x7Fu], 1u);
        }
    }
    __syncthreads();
    if (t == 0) {
        int rem = s_remaining;
        int b = 127;
        for (; b > 0; --b) {
            int c = (int)hist[b];
            if (rem - c <= 0) break;
            rem -= c;
        }
        s_tkey = (b1 << 7) | (unsigned)b;
        s_remaining = rem;
    }
    __syncthreads();

    const unsigned tkey = s_tkey;
    const int      E    = s_remaining;

    // stable tie-break: rank ==tkey entries by ascending index
    const int base = t * 16;
    int cnt = 0;
    #pragma unroll
    for (int j = 0; j < 16; ++j)
        if ((zrow[base + j] & 0x7FFFu) == tkey) cnt++;
    cnts[t] = cnt;
    __syncthreads();
    if (t == 0) {
        int run = 0;
        for (int i = 0; i < 256; ++i) { int c = cnts[i]; cnts[i] = run; run += c; }
    }
    __syncthreads();

    int rank = cnts[t];
    #pragma unroll
    for (int q = 0; q < 2; ++q) {
        u16x8 v;
        #pragma unroll
        for (int j = 0; j < 8; ++j) {
            int f = base + q*8 + j;
            unsigned short raw = zrow[f];
            unsigned key = raw & 0x7FFFu;
            bool sel;
            if (key > tkey)       sel = true;
            else if (key == tkey) { sel = (rank < E); rank++; }
            else                  sel = false;
            v[j] = sel ? raw : (unsigned short)0;
        }
        *(u16x8*)(zp + base + q*8) = v;
    }
}

// ---------------------------------------------------------------------------
// Down-projection, single fp16 MFMA, global_load_lds staged.
// BM=128, BN=128, BK=32. 4 waves (2x2); per-wave 64x64.
// z is a dense fp16 array [CT][DF]; Wd pre-converted fp16.
// LDS ZH/WH [128][32] per buf = 16KB; x2 = 32KB.
// ---------------------------------------------------------------------------
#define OZH 0
#define OWH (128*32)
#define DNBUF (2*128*32)   // 8192 elements = 16KB

__global__ __launch_bounds__(256) void k_gemm_down_mfma(
    const _Float16* __restrict__ z, const _Float16* __restrict__ wdh,
    float* __restrict__ out, int tok0, int nM)
{
    __shared__ _Float16 L[2 * DNBUF];
    const int t = threadIdx.x, lane = t & 63, wid = t >> 6;

    int bid = blockIdx.x, mi, ni;
    if ((nM & 3) == 0) {
        int st = bid >> 4, lo = bid & 15, nstM = nM >> 2;
        mi = ((st % nstM) << 2) + (lo & 3);
        ni = ((st / nstM) << 2) + (lo >> 2);
    } else { mi = bid % nM; ni = bid / nM; }
    const int m0 = mi * 128, d0 = ni * 128;

    const int rr = lane >> 2, slot = lane & 3;
    size_t zoff[2], wof[2];
    #pragma unroll
    for (int q = 0; q < 2; ++q) {
        int row = wid*32 + q*16 + rr;
        int ss  = slot ^ ((row >> 1) & 3);
        zoff[q] = (size_t)(m0 + row) * (DF*2) + ss*16;
        wof[q]  = (size_t)(d0 + row) * (DF*2) + ss*16;
    }
    const char* zB = (const char*)z;
    const char* wB = (const char*)wdh;

    const int wr = wid >> 1, wc = wid & 1;
    const int lrow = lane & 15, lk = (lane >> 4) * 8;

    f32x4 acc[4][4] = {};

    #define DN_STAGE(b, kt) do {                                              \
        _Float16* Lb = L + (b) * DNBUF;                                       \
        size_t ka = (size_t)(kt) * 64;                                        \
        _Pragma("unroll")                                                     \
        for (int q = 0; q < 2; ++q) {                                         \
            GLD16(zB + zoff[q] + ka, Lb + OZH + (wid*32 + q*16)*32);          \
            GLD16(wB + wof[q]  + ka, Lb + OWH + (wid*32 + q*16)*32);          \
        }                                                                     \
    } while (0)

    DN_STAGE(0, 0);
    __syncthreads();

    int buf = 0;
    for (int kt = 0; kt < DF/32; ++kt) {
        if (kt + 1 < DF/32) DN_STAGE(buf ^ 1, kt + 1);
        const _Float16* Lb = &L[buf * DNBUF];
        f16x8 ah[4], bh[4];
        #pragma unroll
        for (int mf = 0; mf < 4; ++mf)
            ah[mf] = *(const f16x8*)&Lb[OZH + swz(wr*64 + mf*16 + lrow, lk)];
        #pragma unroll
        for (int nf = 0; nf < 4; ++nf)
            bh[nf] = *(const f16x8*)&Lb[OWH + swz(wc*64 + nf*16 + lrow, lk)];
        #pragma unroll
        for (int nf = 0; nf < 4; ++nf)
            #pragma unroll
            for (int mf = 0; mf < 4; ++mf)
                acc[mf][nf] = MFMA(ah[mf], bh[nf], acc[mf][nf]);
        __syncthreads();
        buf ^= 1;
    }

    #pragma unroll
    for (int mf = 0; mf < 4; ++mf)
        #pragma unroll
        for (int nf = 0; nf < 4; ++nf)
            #pragma unroll
            for (int r = 0; r < 4; ++r) {
                int row = tok0 + m0 + wr*64 + mf*16 + (lane>>4)*4 + r;
                int col = d0 + wc*64 + nf*16 + lrow;
                out[(size_t)row*NE + col] = acc[mf][nf][r];
            }
    #undef DN_STAGE
}

// ---------------------------------------------------------------------------
extern "C" void kernel_launch(void* const* d_in, const int* in_sizes, int n_in,
                              void* d_out, int out_size, void* d_ws, size_t ws_size,
                              hipStream_t stream)
{
    const float* x  = (const float*)d_in[0];
    const float* Wg = (const float*)d_in[1];
    const float* Wu = (const float*)d_in[2];
    const float* Wd = (const float*)d_in[3];
    float* out = (float*)d_out;

    // fixed-size weights: gh/uh (DF*NE f16) + wdh (NE*DF f16) = 3 arrays
    const size_t wElems = (size_t)DF * NE;
    const size_t fixedBytes = wElems * 2 * 3;   // 25 MB

    // chunk tokens: need z fp16 (CT*DF*2) + xh/xl (CT*NE*2 each) + fixed
    int CT = NTOK;
    while (CT > 128 &&
           (size_t)CT*DF*2 + (size_t)CT*NE*4 + fixedBytes > ws_size) CT >>= 1;

    char* wsb = (char*)d_ws;
    _Float16* zbuf = (_Float16*)wsb;
    _Float16* xh   = (_Float16*)(wsb + (size_t)CT*DF*2);
    _Float16* xl   = xh + (size_t)CT*NE;
    _Float16* gh   = xl + (size_t)CT*NE;
    _Float16* uh   = gh + wElems;
    _Float16* wdh  = uh + wElems;

    // one-time weight prep
    {
        int n8 = (int)(wElems / 8);
        k_cvt1<<<dim3((n8+255)/256), 256, 0, stream>>>(Wg, gh, n8);
        k_cvt1<<<dim3((n8+255)/256), 256, 0, stream>>>(Wu, uh, n8);
        k_cvt1<<<dim3((n8+255)/256), 256, 0, stream>>>(Wd, wdh, n8);
    }

    for (int tok0 = 0; tok0 < NTOK; tok0 += CT) {
        int nM = CT / 128;
        int nx8 = CT * NE / 8;
        k_split2<<<dim3((nx8+255)/256), 256, 0, stream>>>(x + (size_t)tok0*NE, xh, xl, nx8);
        k_gemm_gu_mfma  <<<dim3(nM * (DF/64)),  256, 0, stream>>>(xh, xl, gh, uh, zbuf, nM);
        k_topk_mask16   <<<dim3(CT),            256, 0, stream>>>(zbuf);
        k_gemm_down_mfma<<<dim3(nM * (NE/128)), 256, 0, stream>>>(zbuf, wdh, out, tok0, nM);
    }
}

// Round 12
// 988.481 us; speedup vs baseline: 5.0626x; 1.0031x over previous
//
#include <hip/hip_runtime.h>
#include <cstdint>
#include <cstddef>

#define NE   1024    // N_EMBD
#define DF   4096    // D_FF
#define KACT 1024    // K_ACTIVE
#define NTOK 16384   // B*S

typedef _Float16       f16x8  __attribute__((ext_vector_type(8)));
typedef unsigned short u16x8  __attribute__((ext_vector_type(8)));
typedef float          f32x4  __attribute__((ext_vector_type(4)));
typedef float          f32x16 __attribute__((ext_vector_type(16)));

#define MFMA16(a,b,c) __builtin_amdgcn_mfma_f32_16x16x32_f16(a,b,c,0,0,0)
#define MFMA32(a,b,c) __builtin_amdgcn_mfma_f32_32x32x16_f16(a,b,c,0,0,0)

// async global->LDS, 16B per lane; LDS dest = uniform base + lane*16 (linear)
#define GLD16(gp, lp) __builtin_amdgcn_global_load_lds( \
    (const __attribute__((address_space(1))) unsigned int*)(gp), \
    (__attribute__((address_space(3))) unsigned int*)(lp), 16, 0, 0)

// LDS tiles are [rows][32] f16 (64 B rows, 4x 16B chunks). Chunk-slot XOR
// swizzle chunk' = chunk ^ ((row>>1)&3): measured 0 bank conflicts (r6/r10).
// global_load_lds fills linearly; swizzle applied by pre-swizzling the
// per-lane GLOBAL source chunk (same involution on read).
__device__ __forceinline__ int swz(int row, int lk) {
    return row * 32 + ((((lk) >> 3) ^ ((row >> 1) & 3)) << 3);
}

// split fp32 -> hi fp16 + lo fp16 (residual)
__device__ __forceinline__ void cvt8(const float* f, f16x8& h, f16x8& l) {
    #pragma unroll
    for (int j = 0; j < 8; ++j) {
        _Float16 hh = (_Float16)f[j];
        h[j] = hh;
        l[j] = (_Float16)(f[j] - (float)hh);
    }
}

// ---------------------------------------------------------------------------
// Fused prep (1 launch instead of 4): Wg->gh, Wu->uh, Wd->wdh (fp16),
// x->xh+xl (split). Region-dispatched by flat index.
// ---------------------------------------------------------------------------
__global__ __launch_bounds__(256) void k_prep(
    const float* __restrict__ Wg, const float* __restrict__ Wu,
    const float* __restrict__ Wd, const float* __restrict__ x,
    _Float16* __restrict__ gh, _Float16* __restrict__ uh,
    _Float16* __restrict__ wdh, _Float16* __restrict__ xh,
    _Float16* __restrict__ xl, int nw8, int nx8)
{
    int i = blockIdx.x * 256 + threadIdx.x;
    const float* s; _Float16* dh; _Float16* dl = nullptr; int j;
    if (i < nw8)            { s = Wg; dh = gh;  j = i; }
    else if (i < 2*nw8)     { s = Wu; dh = uh;  j = i - nw8; }
    else if (i < 3*nw8)     { s = Wd; dh = wdh; j = i - 2*nw8; }
    else if (i < 3*nw8+nx8) { s = x;  dh = xh;  dl = xl; j = i - 3*nw8; }
    else return;
    float4 a = ((const float4*)s)[2*j], b = ((const float4*)s)[2*j+1];
    float f[8] = {a.x,a.y,a.z,a.w,b.x,b.y,b.z,b.w};
    if (dl) {
        f16x8 hh, ll; cvt8(f, hh, ll);
        ((f16x8*)dh)[j] = hh; ((f16x8*)dl)[j] = ll;
    } else {
        f16x8 hh;
        #pragma unroll
        for (int q = 0; q < 8; ++q) hh[q] = (_Float16)f[q];
        ((f16x8*)dh)[j] = hh;
    }
}

// ---------------------------------------------------------------------------
// Up-projection via fp16x2 MFMA on the 32x32x16 shape (2495 TF ceiling vs
// 2075 for 16x16; same LDS traffic, -17% issue cycles).
//   acc = xh*W + xl*W (x split h+l, weights single fp16 — r11-verified).
// BM=128 tokens, BN=64 ff, BK=32. 4 waves (2x2); per-wave 64x32 (g and u):
// 2 M-tiles of 32x32 per wave, 2 k-substeps of 16 -> 16 MFMA + 12 ds_read.
// LDS per buf: XH/XL [128][32], GH/UH [64][32] = 24KB; x2 = 48KB.
// A-frag: row=lane&31, k=(lane>>5)*8+e. C/D: col=lane&31,
// row=(reg&3)+8*(reg>>2)+4*(lane>>5) [guide m74/m101].
// ---------------------------------------------------------------------------
#define OXH 0
#define OXL (128*32)
#define OGH (2*128*32)
#define OUH (2*128*32 + 64*32)
#define GUBUF (2*128*32 + 2*64*32)   // 12288 elements = 24KB

__global__ __launch_bounds__(256) void k_gemm_gu_mfma(
    const _Float16* __restrict__ xh, const _Float16* __restrict__ xl,
    const _Float16* __restrict__ gh, const _Float16* __restrict__ uh,
    _Float16* __restrict__ z, int nM)
{
    __shared__ _Float16 L[2 * GUBUF];
    const int t = threadIdx.x, lane = t & 63, wid = t >> 6;

    // 4x4 supertile swizzle for L2 locality
    int bid = blockIdx.x, mi, ni;
    if ((nM & 3) == 0) {
        int st = bid >> 4, lo = bid & 15, nstM = nM >> 2;
        mi = ((st % nstM) << 2) + (lo & 3);
        ni = ((st / nstM) << 2) + (lo >> 2);
    } else { mi = bid % nM; ni = bid / nM; }
    const int m0 = mi * 128, f0 = ni * 64;

    // ---- staging roles (per lane): linear LDS fill, pre-swizzled source ----
    const int rr = lane >> 2, slot = lane & 3;
    size_t xoff[2];
    #pragma unroll
    for (int q = 0; q < 2; ++q) {
        int row = wid*32 + q*16 + rr;
        int ss  = slot ^ ((row >> 1) & 3);
        xoff[q] = (size_t)(m0 + row) * (NE*2) + ss*16;
    }
    size_t woff;   // wave w stages GH and UH rows [w*16, w*16+16)
    {
        int row = wid*16 + rr;
        int ss  = slot ^ ((row >> 1) & 3);
        woff = (size_t)(f0 + row) * (NE*2) + ss*16;
    }
    const char* xhB = (const char*)xh;
    const char* xlB = (const char*)xl;
    const char* ghB = (const char*)gh;
    const char* uhB = (const char*)uh;

    const int wr = wid >> 1, wc = wid & 1;
    const int l31 = lane & 31, lks = (lane >> 5) * 8;   // 32x32 frag coords

    f32x16 accg[2] = {}, accu[2] = {};

    // stage K-step kt into buffer b (6 GLD16/lane; uniform k-advance hoisted)
    #define GU_STAGE(b, kt) do {                                              \
        _Float16* Lb = L + (b) * GUBUF;                                       \
        const size_t ka = (size_t)(kt) * 64;                                  \
        const char* xhK = xhB + ka;  const char* xlK = xlB + ka;              \
        const char* ghK = ghB + ka;  const char* uhK = uhB + ka;              \
        _Pragma("unroll")                                                     \
        for (int q = 0; q < 2; ++q) {                                         \
            GLD16(xhK + xoff[q], Lb + OXH + (wid*32 + q*16)*32);              \
            GLD16(xlK + xoff[q], Lb + OXL + (wid*32 + q*16)*32);              \
        }                                                                     \
        GLD16(ghK + woff, Lb + OGH + (wid*16)*32);                            \
        GLD16(uhK + woff, Lb + OUH + (wid*16)*32);                            \
    } while (0)

    GU_STAGE(0, 0);
    __syncthreads();

    int buf = 0;
    for (int kt = 0; kt < 32; ++kt) {
        if (kt + 1 < 32) GU_STAGE(buf ^ 1, kt + 1);
        const _Float16* Lb = &L[buf * GUBUF];
        f16x8 ah[2][2], al[2][2];   // [ksub][Mtile]
        #pragma unroll
        for (int s = 0; s < 2; ++s)
            #pragma unroll
            for (int mt = 0; mt < 2; ++mt) {
                int off = swz(wr*64 + mt*32 + l31, s*16 + lks);
                ah[s][mt] = *(const f16x8*)&Lb[OXH + off];
                al[s][mt] = *(const f16x8*)&Lb[OXL + off];
            }
        #pragma unroll
        for (int s = 0; s < 2; ++s) {
            int offb = swz(wc*32 + l31, s*16 + lks);
            f16x8 bg = *(const f16x8*)&Lb[OGH + offb];
            f16x8 bu = *(const f16x8*)&Lb[OUH + offb];
            #pragma unroll
            for (int mt = 0; mt < 2; ++mt) {
                accg[mt] = MFMA32(ah[s][mt], bg, accg[mt]);
                accg[mt] = MFMA32(al[s][mt], bg, accg[mt]);
                accu[mt] = MFMA32(ah[s][mt], bu, accu[mt]);
                accu[mt] = MFMA32(al[s][mt], bu, accu[mt]);
            }
        }
        __syncthreads();
        buf ^= 1;
    }

    // epilogue: silu(g)*u with native exp; 32x32 C-layout store
    #pragma unroll
    for (int mt = 0; mt < 2; ++mt)
        #pragma unroll
        for (int r = 0; r < 16; ++r) {
            int row = m0 + wr*64 + mt*32 + (r & 3) + 8*(r >> 2) + 4*(lane >> 5);
            int col = f0 + wc*32 + l31;
            float g = accg[mt][r], u = accu[mt][r];
            float sg = g / (1.0f + __expf(-g));
            z[(size_t)row*DF + col] = (_Float16)(sg * u);
        }
    #undef GU_STAGE
}

// ---------------------------------------------------------------------------
// Exact per-token top-K mask on fp16 z: 2-pass radix select on the 15-bit
// magnitude key; stable ties by ascending index. Masks in place. (r10-verified)
// ---------------------------------------------------------------------------
__global__ __launch_bounds__(256) void k_topk_mask16(_Float16* __restrict__ z)
{
    __shared__ unsigned short zrow[DF];
    __shared__ unsigned hist[256];
    __shared__ int      cnts[256];
    __shared__ unsigned s_b1;
    __shared__ unsigned s_tkey;
    __shared__ int      s_remaining;

    const int t = threadIdx.x;
    unsigned short* zp = (unsigned short*)(z + (size_t)blockIdx.x * DF);

    for (int i = t; i < DF/8; i += 256) {
        ((ushort4*)zrow)[2*i]   = ((const ushort4*)zp)[2*i];
        ((ushort4*)zrow)[2*i+1] = ((const ushort4*)zp)[2*i+1];
    }
    if (t == 0) s_remaining = KACT;
    __syncthreads();

    hist[t] = 0u;
    __syncthreads();
    {
        const int base = t * 16;
        #pragma unroll
        for (int j = 0; j < 16; ++j) {
            unsigned key = zrow[base + j] & 0x7FFFu;
            atomicAdd(&hist[key >> 7], 1u);
        }
    }
    __syncthreads();
    if (t == 0) {
        int rem = s_remaining;
        int b = 255;
        for (; b > 0; --b) {
            int c = (int)hist[b];
            if (rem - c <= 0) break;
            rem -= c;
        }
        s_b1 = (unsigned)b;
        s_remaining = rem;
    }
    __syncthreads();

    const unsigned b1 = s_b1;
    hist[t] = 0u;
    __syncthreads();
    {
        const int base = t * 16;
        #pragma unroll
        for (int j = 0; j < 16; ++j) {
            unsigned key = zrow[base + j] & 0x7FFFu;
            if ((key >> 7) == b1) atomicAdd(&hist[key & 0x7Fu], 1u);
        }
    }
    __syncthreads();
    if (t == 0) {
        int rem = s_remaining;
        int b = 127;
        for (; b > 0; --b) {
            int c = (int)hist[b];
            if (rem - c <= 0) break;
            rem -= c;
        }
        s_tkey = (b1 << 7) | (unsigned)b;
        s_remaining = rem;
    }
    __syncthreads();

    const unsigned tkey = s_tkey;
    const int      E    = s_remaining;

    const int base = t * 16;
    int cnt = 0;
    #pragma unroll
    for (int j = 0; j < 16; ++j)
        if ((zrow[base + j] & 0x7FFFu) == tkey) cnt++;
    cnts[t] = cnt;
    __syncthreads();
    if (t == 0) {
        int run = 0;
        for (int i = 0; i < 256; ++i) { int c = cnts[i]; cnts[i] = run; run += c; }
    }
    __syncthreads();

    int rank = cnts[t];
    #pragma unroll
    for (int q = 0; q < 2; ++q) {
        u16x8 v;
        #pragma unroll
        for (int j = 0; j < 8; ++j) {
            int f = base + q*8 + j;
            unsigned short raw = zrow[f];
            unsigned key = raw & 0x7FFFu;
            bool sel;
            if (key > tkey)       sel = true;
            else if (key == tkey) { sel = (rank < E); rank++; }
            else                  sel = false;
            v[j] = sel ? raw : (unsigned short)0;
        }
        *(u16x8*)(zp + base + q*8) = v;
    }
}

// ---------------------------------------------------------------------------
// Down-projection, single fp16 16x16x32 MFMA, global_load_lds staged.
// (unchanged from r11-verified kernel)
// ---------------------------------------------------------------------------
#define OZH 0
#define OWH (128*32)
#define DNBUF (2*128*32)   // 8192 elements = 16KB

__global__ __launch_bounds__(256) void k_gemm_down_mfma(
    const _Float16* __restrict__ z, const _Float16* __restrict__ wdh,
    float* __restrict__ out, int tok0, int nM)
{
    __shared__ _Float16 L[2 * DNBUF];
    const int t = threadIdx.x, lane = t & 63, wid = t >> 6;

    int bid = blockIdx.x, mi, ni;
    if ((nM & 3) == 0) {
        int st = bid >> 4, lo = bid & 15, nstM = nM >> 2;
        mi = ((st % nstM) << 2) + (lo & 3);
        ni = ((st / nstM) << 2) + (lo >> 2);
    } else { mi = bid % nM; ni = bid / nM; }
    const int m0 = mi * 128, d0 = ni * 128;

    const int rr = lane >> 2, slot = lane & 3;
    size_t zoff[2], wof[2];
    #pragma unroll
    for (int q = 0; q < 2; ++q) {
        int row = wid*32 + q*16 + rr;
        int ss  = slot ^ ((row >> 1) & 3);
        zoff[q] = (size_t)(m0 + row) * (DF*2) + ss*16;
        wof[q]  = (size_t)(d0 + row) * (DF*2) + ss*16;
    }
    const char* zB = (const char*)z;
    const char* wB = (const char*)wdh;

    const int wr = wid >> 1, wc = wid & 1;
    const int lrow = lane & 15, lk = (lane >> 4) * 8;

    f32x4 acc[4][4] = {};

    #define DN_STAGE(b, kt) do {                                              \
        _Float16* Lb = L + (b) * DNBUF;                                       \
        size_t ka = (size_t)(kt) * 64;                                        \
        _Pragma("unroll")                                                     \
        for (int q = 0; q < 2; ++q) {                                         \
            GLD16(zB + zoff[q] + ka, Lb + OZH + (wid*32 + q*16)*32);          \
            GLD16(wB + wof[q]  + ka, Lb + OWH + (wid*32 + q*16)*32);          \
        }                                                                     \
    } while (0)

    DN_STAGE(0, 0);
    __syncthreads();

    int buf = 0;
    for (int kt = 0; kt < DF/32; ++kt) {
        if (kt + 1 < DF/32) DN_STAGE(buf ^ 1, kt + 1);
        const _Float16* Lb = &L[buf * DNBUF];
        f16x8 ah[4], bh[4];
        #pragma unroll
        for (int mf = 0; mf < 4; ++mf)
            ah[mf] = *(const f16x8*)&Lb[OZH + swz(wr*64 + mf*16 + lrow, lk)];
        #pragma unroll
        for (int nf = 0; nf < 4; ++nf)
            bh[nf] = *(const f16x8*)&Lb[OWH + swz(wc*64 + nf*16 + lrow, lk)];
        #pragma unroll
        for (int nf = 0; nf < 4; ++nf)
            #pragma unroll
            for (int mf = 0; mf < 4; ++mf)
                acc[mf][nf] = MFMA16(ah[mf], bh[nf], acc[mf][nf]);
        __syncthreads();
        buf ^= 1;
    }

    #pragma unroll
    for (int mf = 0; mf < 4; ++mf)
        #pragma unroll
        for (int nf = 0; nf < 4; ++nf)
            #pragma unroll
            for (int r = 0; r < 4; ++r) {
                int row = tok0 + m0 + wr*64 + mf*16 + (lane>>4)*4 + r;
                int col = d0 + wc*64 + nf*16 + lrow;
                out[(size_t)row*NE + col] = acc[mf][nf][r];
            }
    #undef DN_STAGE
}

// ---------------------------------------------------------------------------
extern "C" void kernel_launch(void* const* d_in, const int* in_sizes, int n_in,
                              void* d_out, int out_size, void* d_ws, size_t ws_size,
                              hipStream_t stream)
{
    const float* x  = (const float*)d_in[0];
    const float* Wg = (const float*)d_in[1];
    const float* Wu = (const float*)d_in[2];
    const float* Wd = (const float*)d_in[3];
    float* out = (float*)d_out;

    // fixed-size weights: gh/uh (DF*NE f16) + wdh (NE*DF f16) = 3 arrays
    const size_t wElems = (size_t)DF * NE;
    const size_t fixedBytes = wElems * 2 * 3;   // 25 MB

    // chunk tokens: need z fp16 (CT*DF*2) + xh/xl (CT*NE*2 each) + fixed
    int CT = NTOK;
    while (CT > 128 &&
           (size_t)CT*DF*2 + (size_t)CT*NE*4 + fixedBytes > ws_size) CT >>= 1;

    char* wsb = (char*)d_ws;
    _Float16* zbuf = (_Float16*)wsb;
    _Float16* xh   = (_Float16*)(wsb + (size_t)CT*DF*2);
    _Float16* xl   = xh + (size_t)CT*NE;
    _Float16* gh   = xl + (size_t)CT*NE;
    _Float16* uh   = gh + wElems;
    _Float16* wdh  = uh + wElems;

    const int nw8 = (int)(wElems / 8);

    for (int tok0 = 0; tok0 < NTOK; tok0 += CT) {
        int nM  = CT / 128;
        int nx8 = CT * NE / 8;
        int nPrep = 3*nw8 + nx8;
        k_prep<<<dim3((nPrep+255)/256), 256, 0, stream>>>(
            Wg, Wu, Wd, x + (size_t)tok0*NE, gh, uh, wdh, xh, xl, nw8, nx8);
        k_gemm_gu_mfma  <<<dim3(nM * (DF/64)),  256, 0, stream>>>(xh, xl, gh, uh, zbuf, nM);
        k_topk_mask16   <<<dim3(CT),            256, 0, stream>>>(zbuf);
        k_gemm_down_mfma<<<dim3(nM * (NE/128)), 256, 0, stream>>>(zbuf, wdh, out, tok0, nM);
    }
}